// Round 7
// baseline (1171.142 us; speedup 1.0000x reference)
//
#include <hip/hip_runtime.h>

#ifndef BATCH
#define BATCH 16
#endif

// ---- DPP wave64 reduction helpers (row_shr scan + row_bcast merge) --------
template<int CTRL>
__device__ __forceinline__ float dppmaxf(float v)
{
    const int d = __builtin_amdgcn_update_dpp(__float_as_int(v), __float_as_int(v),
                                              CTRL, 0xf, 0xf, false);
    return fmaxf(v, __int_as_float(d));
}
template<int CTRL>
__device__ __forceinline__ unsigned dppminu(unsigned v)
{
    const unsigned d = (unsigned)__builtin_amdgcn_update_dpp((int)v, (int)v,
                                                             CTRL, 0xf, 0xf, false);
    return (d < v) ? d : v;
}
// full-wave max of v -> wave-uniform result (via lane 63)
__device__ __forceinline__ float wave_max_bcast(float v)
{
    v = dppmaxf<0x111>(v);  // row_shr:1
    v = dppmaxf<0x112>(v);  // row_shr:2
    v = dppmaxf<0x114>(v);  // row_shr:4
    v = dppmaxf<0x118>(v);  // row_shr:8
    v = dppmaxf<0x142>(v);  // row_bcast:15
    v = dppmaxf<0x143>(v);  // row_bcast:31
    return __int_as_float(__builtin_amdgcn_readlane(__float_as_int(v), 63));
}
__device__ __forceinline__ unsigned wave_min_bcast(unsigned v)
{
    v = dppminu<0x111>(v);
    v = dppminu<0x112>(v);
    v = dppminu<0x114>(v);
    v = dppminu<0x118>(v);
    v = dppminu<0x142>(v);
    v = dppminu<0x143>(v);
    return (unsigned)__builtin_amdgcn_readlane((int)v, 63);
}

// ---------------------------------------------------------------------------
// Fused FPS (both stages). One block per batch, BLOCK=256 (1 wave/SIMD).
// Per step (one barrier, no atomics): dist update (P pts/thread); DPP
// value-max + index-min wave reduce; wave lane0 fetches candidate coords and
// publishes record {pk,x,y,z} to parity double-buffered wavemax[2][NW];
// after barrier all threads broadcast-read the NW records and pick the
// winner via cndmask tree -> coords arrive with the record (no dependent
// sx[far] lookup). Parity buffer is race-free: writes of step s+2 to buffer
// (s&1) are separated from step-s reads by barrier s+1.
// Bit-exact: contract(off), (dx*dx+dy*dy)+dz*dz, strict-> first-index argmax
// (pk = dist_bits<<32 | ~idx; indices disjoint across waves -> no u64 ties).
// ---------------------------------------------------------------------------
template<int N, int NP1, int NP2, int BLOCK>
__global__ __launch_bounds__(BLOCK)
void fps_fused(const float* __restrict__ xyz,
               float* __restrict__ out1, float* __restrict__ out2)
{
#pragma clang fp contract(off)
    constexpr int P  = N / BLOCK;     // stage-1 points per thread
    constexpr int P2 = NP1 / BLOCK;   // stage-2 points per thread
    constexpr int NW = BLOCK / 64;    // waves per block
    __shared__ float sx[N], sy[N], sz[N];
    __shared__ float s2x[NP1], s2y[NP1], s2z[NP1];
    __shared__ unsigned long long wpk[2][NW];
    __shared__ float wcx[2][NW], wcy[2][NW], wcz[2][NW];
    const int b = blockIdx.x, t = threadIdx.x;
    const int lane = t & 63, wv = t >> 6;
    const float* xb = xyz + (size_t)b * N * 3;
    float px[P], py[P], pz[P], dist[P];
#pragma unroll
    for (int j = 0; j < P; ++j) {
        const int i = t + j * BLOCK;
        const float x = xb[i*3+0], y = xb[i*3+1], z = xb[i*3+2];
        sx[i] = x; sy[i] = y; sz[i] = z;
        px[j] = x; py[j] = y; pz[j] = z;
        dist[j] = 1e10f;
    }
    __syncthreads();
    float fx = sx[0], fy = sy[0], fz = sz[0];
    if (t == 0) {
        out1[(size_t)b*NP1*3 + 0] = fx;
        out1[(size_t)b*NP1*3 + 1] = fy;
        out1[(size_t)b*NP1*3 + 2] = fz;
        s2x[0] = fx; s2y[0] = fy; s2z[0] = fz;
    }
    for (int s = 1; s < NP1; ++s) {
        float bestv = -1.f; int besti = 0;
#pragma unroll
        for (int j = 0; j < P; ++j) {
            const float dx = px[j]-fx, dy = py[j]-fy, dz = pz[j]-fz;
            const float d = (dx*dx + dy*dy) + dz*dz;
            const float nd = fminf(dist[j], d);
            dist[j] = nd;
            if (nd > bestv) { bestv = nd; besti = t + j * BLOCK; }  // first idx kept
        }
        const float wm = wave_max_bcast(bestv);
        const unsigned cand = (bestv == wm) ? (unsigned)besti : 0xffffffffu;
        const unsigned wi = wave_min_bcast(cand);
        const int par = s & 1;
        if (lane == 0) {
            wpk[par][wv] = ((unsigned long long)__float_as_uint(wm) << 32)
                         | (unsigned)(~wi);
            wcx[par][wv] = sx[wi]; wcy[par][wv] = sy[wi]; wcz[par][wv] = sz[wi];
        }
        __syncthreads();
        unsigned long long pa = wpk[par][0];
        float xa = wcx[par][0], ya = wcy[par][0], za = wcz[par][0];
#pragma unroll
        for (int w = 1; w < NW; ++w) {
            const unsigned long long pb = wpk[par][w];
            const float xw = wcx[par][w], yw = wcy[par][w], zw = wcz[par][w];
            if (pb > pa) { pa = pb; xa = xw; ya = yw; za = zw; }
        }
        fx = xa; fy = ya; fz = za;
        if (t == 0) {
            out1[((size_t)b*NP1 + s)*3 + 0] = xa;
            out1[((size_t)b*NP1 + s)*3 + 1] = ya;
            out1[((size_t)b*NP1 + s)*3 + 2] = za;
            s2x[s] = xa; s2y[s] = ya; s2z[s] = za;
        }
    }
    __syncthreads();             // s2 arrays complete
    // -------- stage 2: FPS over NP1 sampled points (P2 per thread) ----------
    float mx[P2], my[P2], mz[P2], d2[P2];
#pragma unroll
    for (int j = 0; j < P2; ++j) {
        const int i = t + j * BLOCK;
        mx[j] = s2x[i]; my[j] = s2y[i]; mz[j] = s2z[i];
        d2[j] = 1e10f;
    }
    fx = s2x[0]; fy = s2y[0]; fz = s2z[0];
    if (t == 0) {
        out2[(size_t)b*NP2*3 + 0] = fx;
        out2[(size_t)b*NP2*3 + 1] = fy;
        out2[(size_t)b*NP2*3 + 2] = fz;
    }
    for (int s = 1; s < NP2; ++s) {
        float bestv = -1.f; int besti = 0;
#pragma unroll
        for (int j = 0; j < P2; ++j) {
            const float dx = mx[j]-fx, dy = my[j]-fy, dz = mz[j]-fz;
            const float d = (dx*dx + dy*dy) + dz*dz;
            const float nd = fminf(d2[j], d);
            d2[j] = nd;
            if (nd > bestv) { bestv = nd; besti = t + j * BLOCK; }
        }
        const float wm = wave_max_bcast(bestv);
        const unsigned cand = (bestv == wm) ? (unsigned)besti : 0xffffffffu;
        const unsigned wi = wave_min_bcast(cand);
        const int par = s & 1;
        if (lane == 0) {
            wpk[par][wv] = ((unsigned long long)__float_as_uint(wm) << 32)
                         | (unsigned)(~wi);
            wcx[par][wv] = s2x[wi]; wcy[par][wv] = s2y[wi]; wcz[par][wv] = s2z[wi];
        }
        __syncthreads();
        unsigned long long pa = wpk[par][0];
        float xa = wcx[par][0], ya = wcy[par][0], za = wcz[par][0];
#pragma unroll
        for (int w = 1; w < NW; ++w) {
            const unsigned long long pb = wpk[par][w];
            const float xw = wcx[par][w], yw = wcy[par][w], zw = wcz[par][w];
            if (pb > pa) { pa = pb; xa = xw; ya = yw; za = zw; }
        }
        fx = xa; fy = ya; fz = za;
        if (t == 0) {
            out2[((size_t)b*NP2 + s)*3 + 0] = xa;
            out2[((size_t)b*NP2 + s)*3 + 1] = ya;
            out2[((size_t)b*NP2 + s)*3 + 2] = za;
        }
    }
}

// ---------------------------------------------------------------------------
// Ball query (unchanged, known-correct)
// ---------------------------------------------------------------------------
template<int N, int S, int K>
__global__ __launch_bounds__(256)
void ballq_kernel(const float* __restrict__ xyz, const float* __restrict__ nxyz,
                  int* __restrict__ idx, const float r2)
{
#pragma clang fp contract(off)
    const int gw = (blockIdx.x * 256 + threadIdx.x) >> 6;
    const int lane = threadIdx.x & 63;
    const int b = gw / S, s = gw % S;
    const float* xb = xyz + (size_t)b * N * 3;
    const float qx = nxyz[((size_t)b*S + s)*3 + 0];
    const float qy = nxyz[((size_t)b*S + s)*3 + 1];
    const float qz = nxyz[((size_t)b*S + s)*3 + 2];
    int* op = idx + ((size_t)b*S + s) * K;
    int base = 0, first = -1;
    for (int c = 0; c < N; c += 64) {
        const int i = c + lane;
        const float dx = xb[i*3+0]-qx, dy = xb[i*3+1]-qy, dz = xb[i*3+2]-qz;
        const float d = (dx*dx + dy*dy) + dz*dz;
        const bool hit = !(d > r2);
        const unsigned long long m = __ballot(hit);
        if (first < 0 && m) first = c + __builtin_ctzll(m);
        const int pos = base + __popcll(m & ((1ull << lane) - 1ull));
        if (hit && pos < K) op[pos] = i;
        base += __popcll(m);
        if (base >= K) break;
    }
    if (base < K && lane >= base && lane < K) op[lane] = first;
}

// ---------------------------------------------------------------------------
// All 9 weight transposes W[O][C] -> Wt[C][O] in one launch.
// ---------------------------------------------------------------------------
__global__ __launch_bounds__(256)
void transpose_all(const float* __restrict__ s0, float* __restrict__ d0,
                   const float* __restrict__ s1, float* __restrict__ d1,
                   const float* __restrict__ s2, float* __restrict__ d2,
                   const float* __restrict__ s3, float* __restrict__ d3,
                   const float* __restrict__ s4, float* __restrict__ d4,
                   const float* __restrict__ s5, float* __restrict__ d5,
                   const float* __restrict__ s6, float* __restrict__ d6,
                   const float* __restrict__ s7, float* __restrict__ d7,
                   const float* __restrict__ s8, float* __restrict__ d8)
{
    int i = blockIdx.x * 256 + threadIdx.x;
    if (i < 192)    { d0[(i%3)  *64   + i/3  ] = s0[i]; return; }  i -= 192;
    if (i < 4096)   { d1[(i&63) *64   + (i>>6)] = s1[i]; return; } i -= 4096;
    if (i < 8192)   { d2[(i&63) *128  + (i>>6)] = s2[i]; return; } i -= 8192;
    if (i < 16768)  { d3[(i%131)*128  + i/131] = s3[i]; return; }  i -= 16768;
    if (i < 16384)  { d4[(i&127)*128  + (i>>7)] = s4[i]; return; } i -= 16384;
    if (i < 32768)  { d5[(i&127)*256  + (i>>7)] = s5[i]; return; } i -= 32768;
    if (i < 66304)  { d6[(i%259)*256  + i/259] = s6[i]; return; }  i -= 66304;
    if (i < 131072) { d7[(i&255)*512  + (i>>8)] = s7[i]; return; } i -= 131072;
    if (i < 524288) { d8[(i&511)*1024 + (i>>9)] = s8[i]; return; }
}

// 16 FMAs against 16 contiguous transposed weights (4x float4, 16B-aligned)
__device__ __forceinline__ void fma16(float (&acc)[16], const float f,
                                      const float* __restrict__ wrow)
{
    const float4 w0 = ((const float4*)wrow)[0];
    const float4 w1 = ((const float4*)wrow)[1];
    const float4 w2 = ((const float4*)wrow)[2];
    const float4 w3 = ((const float4*)wrow)[3];
    acc[0]+=f*w0.x;  acc[1]+=f*w0.y;  acc[2]+=f*w0.z;  acc[3]+=f*w0.w;
    acc[4]+=f*w1.x;  acc[5]+=f*w1.y;  acc[6]+=f*w1.z;  acc[7]+=f*w1.w;
    acc[8]+=f*w2.x;  acc[9]+=f*w2.y;  acc[10]+=f*w2.z; acc[11]+=f*w2.w;
    acc[12]+=f*w3.x; acc[13]+=f*w3.y; acc[14]+=f*w3.z; acc[15]+=f*w3.w;
}

// ---------------------------------------------------------------------------
// SA1 fused (unchanged)
// ---------------------------------------------------------------------------
__global__ __launch_bounds__(256)
void sa1_fused(const float* __restrict__ xyz, const float* __restrict__ nxyz,
               const int* __restrict__ idx,
               const float* __restrict__ Wt0, const float* __restrict__ B0,
               const float* __restrict__ Wt1, const float* __restrict__ B1,
               const float* __restrict__ Wt2, const float* __restrict__ B2,
               float* __restrict__ out)
{
    __shared__ float h1S[64][64];
    __shared__ float h2S[64][64];
    const int tid = threadIdx.x, lane = tid & 63;
    const int wave = __builtin_amdgcn_readfirstlane(tid >> 6);
    const int row0 = blockIdx.x * 64;
    const int myrow = row0 + lane;
    const int g = myrow >> 5, b = g >> 9;
    const int i = idx[myrow];
    const float* p = xyz + ((size_t)b*4096 + i) * 3;
    const float f0 = p[0] - nxyz[(size_t)g*3 + 0];
    const float f1 = p[1] - nxyz[(size_t)g*3 + 1];
    const float f2 = p[2] - nxyz[(size_t)g*3 + 2];
    const int oc0 = wave * 16;
    float acc[16];
#pragma unroll
    for (int j = 0; j < 16; ++j)
        acc[j] = B0[oc0+j] + f0*Wt0[0*64+oc0+j] + f1*Wt0[1*64+oc0+j] + f2*Wt0[2*64+oc0+j];
#pragma unroll
    for (int j = 0; j < 16; ++j) h1S[oc0+j][lane] = fmaxf(acc[j], 0.f);
    __syncthreads();
#pragma unroll
    for (int j = 0; j < 16; ++j) acc[j] = B1[oc0+j];
#pragma unroll 4
    for (int ci = 0; ci < 64; ++ci)
        fma16(acc, h1S[ci][lane], Wt1 + ci*64 + oc0);
#pragma unroll
    for (int j = 0; j < 16; ++j) h2S[oc0+j][lane] = fmaxf(acc[j], 0.f);
    __syncthreads();
    for (int pass = 0; pass < 2; ++pass) {
        const int oc = pass*64 + oc0;
#pragma unroll
        for (int j = 0; j < 16; ++j) acc[j] = B2[oc+j];
#pragma unroll 4
        for (int ci = 0; ci < 64; ++ci)
            fma16(acc, h2S[ci][lane], Wt2 + ci*128 + oc);
#pragma unroll
        for (int j = 0; j < 16; ++j) {
            float v = fmaxf(acc[j], 0.f);
            v = fmaxf(v, __shfl_xor(v, 1));
            v = fmaxf(v, __shfl_xor(v, 2));
            v = fmaxf(v, __shfl_xor(v, 4));
            v = fmaxf(v, __shfl_xor(v, 8));
            v = fmaxf(v, __shfl_xor(v, 16));
            if ((lane & 31) == 0)
                out[(size_t)((row0 + lane) >> 5) * 128 + oc + j] = v;
        }
    }
}

// ---------------------------------------------------------------------------
// SA2 fused (unchanged)
// ---------------------------------------------------------------------------
__global__ __launch_bounds__(256)
void sa2_fused(const float* __restrict__ l1xyz, const float* __restrict__ l1pts,
               const float* __restrict__ nxyz, const int* __restrict__ idx,
               const float* __restrict__ Wt0, const float* __restrict__ B0,
               const float* __restrict__ Wt1, const float* __restrict__ B1,
               const float* __restrict__ Wt2, const float* __restrict__ B2,
               float* __restrict__ out)
{
    __shared__ float featS[128][64];
    __shared__ float hS[128][64];
    const int tid = threadIdx.x, lane = tid & 63;
    const int wave = __builtin_amdgcn_readfirstlane(tid >> 6);
    const int gblk = blockIdx.x;
    const int b = gblk >> 7;
    const int row0 = gblk * 64;
    const int myi = idx[row0 + lane];
    const float* pc = l1xyz + ((size_t)b*512 + myi) * 3;
    const float f0 = pc[0] - nxyz[(size_t)gblk*3 + 0];
    const float f1 = pc[1] - nxyz[(size_t)gblk*3 + 1];
    const float f2 = pc[2] - nxyz[(size_t)gblk*3 + 2];
    for (int r = wave; r < 64; r += 4) {
        const int i2 = idx[row0 + r];
        const float* src = l1pts + ((size_t)b*512 + i2) * 128;
        featS[lane][r ^ lane]    = src[lane];
        featS[lane+64][r ^ lane] = src[lane + 64];
    }
    __syncthreads();
    const int oc0 = wave * 16;
    float acc[16];
    for (int pass = 0; pass < 2; ++pass) {
        const int oc = pass*64 + oc0;
#pragma unroll
        for (int j = 0; j < 16; ++j)
            acc[j] = B0[oc+j] + f0*Wt0[0*128+oc+j] + f1*Wt0[1*128+oc+j] + f2*Wt0[2*128+oc+j];
#pragma unroll 4
        for (int ci = 0; ci < 128; ++ci)
            fma16(acc, featS[ci][lane ^ (ci & 63)], Wt0 + (size_t)(ci+3)*128 + oc);
#pragma unroll
        for (int j = 0; j < 16; ++j) hS[oc+j][lane] = fmaxf(acc[j], 0.f);
    }
    __syncthreads();
    for (int pass = 0; pass < 2; ++pass) {
        const int oc = pass*64 + oc0;
#pragma unroll
        for (int j = 0; j < 16; ++j) acc[j] = B1[oc+j];
#pragma unroll 4
        for (int ci = 0; ci < 128; ++ci)
            fma16(acc, hS[ci][lane], Wt1 + (size_t)ci*128 + oc);
#pragma unroll
        for (int j = 0; j < 16; ++j) featS[oc+j][lane] = fmaxf(acc[j], 0.f);
    }
    __syncthreads();
    float* orow = out + (size_t)gblk * 256;
    for (int pass = 0; pass < 4; ++pass) {
        const int oc = pass*64 + oc0;
#pragma unroll
        for (int j = 0; j < 16; ++j) acc[j] = B2[oc+j];
#pragma unroll 4
        for (int ci = 0; ci < 128; ++ci)
            fma16(acc, featS[ci][lane], Wt2 + (size_t)ci*256 + oc);
#pragma unroll
        for (int j = 0; j < 16; ++j) {
            float v = fmaxf(acc[j], 0.f);
            v = fmaxf(v, __shfl_xor(v, 1));
            v = fmaxf(v, __shfl_xor(v, 2));
            v = fmaxf(v, __shfl_xor(v, 4));
            v = fmaxf(v, __shfl_xor(v, 8));
            v = fmaxf(v, __shfl_xor(v, 16));
            v = fmaxf(v, __shfl_xor(v, 32));
            if (lane == 0) orow[oc + j] = v;
        }
    }
}

// ---------------------------------------------------------------------------
// SA3 GEMM layers (unchanged)
// ---------------------------------------------------------------------------
template<int CIN, int COUT, bool CONCAT3, bool POOL>
__global__ __launch_bounds__(256)
void mlp_gemm_kernel(const float* __restrict__ inA, const float* __restrict__ inB,
                     const float* __restrict__ Wt, const float* __restrict__ Bb,
                     float* __restrict__ out)
{
    __shared__ float featS[128][64];
    const int tid = threadIdx.x, lane = tid & 63;
    const int wave = __builtin_amdgcn_readfirstlane(tid >> 6);
    const int row0 = blockIdx.x * 64;
    const int oc0 = blockIdx.y * 64 + wave * 16;
    float acc[16];
#pragma unroll
    for (int j = 0; j < 16; ++j) acc[j] = Bb[oc0 + j];
    for (int c0 = 0; c0 < CIN; c0 += 128) {
        const int csz = (CIN - c0 < 128) ? (CIN - c0) : 128;
        __syncthreads();
        for (int r = wave; r < 64; r += 4) {
            const int row = row0 + r;
            for (int cl = lane; cl < csz; cl += 64) {
                const int cig = c0 + cl;
                float v;
                if (CONCAT3)
                    v = (cig < 3) ? inA[(size_t)row*3 + cig]
                                  : inB[(size_t)row*(CIN-3) + (cig - 3)];
                else
                    v = inA[(size_t)row*CIN + cig];
                featS[cl][r ^ (cl & 63)] = v;
            }
        }
        __syncthreads();
        if (csz == 128) {
#pragma unroll 4
            for (int ci = 0; ci < 128; ++ci)
                fma16(acc, featS[ci][lane ^ (ci & 63)], Wt + (size_t)(c0+ci)*COUT + oc0);
        } else {
            for (int ci = 0; ci < csz; ++ci)
                fma16(acc, featS[ci][lane ^ (ci & 63)], Wt + (size_t)(c0+ci)*COUT + oc0);
        }
    }
    if (POOL) {
#pragma unroll
        for (int j = 0; j < 16; ++j) {
            float v = fmaxf(acc[j], 0.f);
            v = fmaxf(v, __shfl_xor(v, 1));
            v = fmaxf(v, __shfl_xor(v, 2));
            v = fmaxf(v, __shfl_xor(v, 4));
            v = fmaxf(v, __shfl_xor(v, 8));
            v = fmaxf(v, __shfl_xor(v, 16));
            v = fmaxf(v, __shfl_xor(v, 32));
            if (lane == 0) out[(size_t)blockIdx.x * COUT + oc0 + j] = v;
        }
    } else {
        float4 o0, o1, o2, o3;
        o0.x=fmaxf(acc[0],0.f);  o0.y=fmaxf(acc[1],0.f);  o0.z=fmaxf(acc[2],0.f);  o0.w=fmaxf(acc[3],0.f);
        o1.x=fmaxf(acc[4],0.f);  o1.y=fmaxf(acc[5],0.f);  o1.z=fmaxf(acc[6],0.f);  o1.w=fmaxf(acc[7],0.f);
        o2.x=fmaxf(acc[8],0.f);  o2.y=fmaxf(acc[9],0.f);  o2.z=fmaxf(acc[10],0.f); o2.w=fmaxf(acc[11],0.f);
        o3.x=fmaxf(acc[12],0.f); o3.y=fmaxf(acc[13],0.f); o3.z=fmaxf(acc[14],0.f); o3.w=fmaxf(acc[15],0.f);
        float4* op = (float4*)(out + (size_t)(row0 + lane)*COUT + oc0);
        op[0]=o0; op[1]=o1; op[2]=o2; op[3]=o3;
    }
}

// y[b][o] = fb[o] + max(pmax[2b], pmax[2b+1]) . fw[o]; one wave per output
__global__ __launch_bounds__(256)
void fc_kernel(const float* __restrict__ pmax, const float* __restrict__ fw,
               const float* __restrict__ fb, float* __restrict__ y)
{
    const int gw = (blockIdx.x * 256 + threadIdx.x) >> 6;
    const int lane = threadIdx.x & 63;
    const int b = gw >> 10, o = gw & 1023;
    const float4* g0 = (const float4*)(pmax + (size_t)(2*b) * 1024);
    const float4* g1 = (const float4*)(pmax + (size_t)(2*b+1) * 1024);
    const float4* wv = (const float4*)(fw + (size_t)o * 1024);
    float acc = 0.f;
#pragma unroll
    for (int r = 0; r < 4; ++r) {
        const float4 a = g0[lane + r*64];
        const float4 c = g1[lane + r*64];
        const float4 w = wv[lane + r*64];
        acc += fmaxf(a.x,c.x)*w.x + fmaxf(a.y,c.y)*w.y
             + fmaxf(a.z,c.z)*w.z + fmaxf(a.w,c.w)*w.w;
    }
#pragma unroll
    for (int m = 32; m >= 1; m >>= 1) acc += __shfl_xor(acc, m);
    if (lane == 0) y[gw] = acc + fb[o];
}

extern "C" void kernel_launch(void* const* d_in, const int* in_sizes, int n_in,
                              void* d_out, int out_size, void* d_ws, size_t ws_size,
                              hipStream_t stream)
{
    (void)in_sizes; (void)n_in; (void)out_size; (void)ws_size;
    const float* x   = (const float*)d_in[0];
    const float* s1w0 = (const float*)d_in[1];  const float* s1b0 = (const float*)d_in[2];
    const float* s1w1 = (const float*)d_in[3];  const float* s1b1 = (const float*)d_in[4];
    const float* s1w2 = (const float*)d_in[5];  const float* s1b2 = (const float*)d_in[6];
    const float* s2w0 = (const float*)d_in[7];  const float* s2b0 = (const float*)d_in[8];
    const float* s2w1 = (const float*)d_in[9];  const float* s2b1 = (const float*)d_in[10];
    const float* s2w2 = (const float*)d_in[11]; const float* s2b2 = (const float*)d_in[12];
    const float* s3w0 = (const float*)d_in[13]; const float* s3b0 = (const float*)d_in[14];
    const float* s3w1 = (const float*)d_in[15]; const float* s3b1 = (const float*)d_in[16];
    const float* s3w2 = (const float*)d_in[17]; const float* s3b2 = (const float*)d_in[18];
    const float* fw  = (const float*)d_in[19]; const float* fb  = (const float*)d_in[20];
    float* y = (float*)d_out;

    char* ws = (char*)d_ws;
    float* l1_xyz = (float*)(ws + 0);          // 16*512*3
    int*   idx1   = (int*)  (ws + 98304);      // 16*512*32
    float* l1_pts = (float*)(ws + 1146880);    // 16*512*128
    float* l2_xyz = (float*)(ws + 5341184);    // 16*128*3
    int*   idx2   = (int*)  (ws + 5365760);    // 16*128*64
    float* l2_pts = (float*)(ws + 5890048);    // 16*128*256
    float* h1     = (float*)(ws + 7987200);    // 2048*256
    float* h2     = (float*)(ws + 10084352);   // 2048*512
    float* pmax   = (float*)(ws + 14278656);   // 32*1024 partial maxes
    float* wt1_0  = (float*)(ws + 14409728);   // [3][64]
    float* wt1_1  = (float*)(ws + 14410496);   // [64][64]
    float* wt1_2  = (float*)(ws + 14426880);   // [64][128]
    float* wt2_0  = (float*)(ws + 14459648);   // [131][128]
    float* wt2_1  = (float*)(ws + 14526720);   // [128][128]
    float* wt2_2  = (float*)(ws + 14592256);   // [128][256]
    float* wt3_0  = (float*)(ws + 14723328);   // [259][256]
    float* wt3_1  = (float*)(ws + 14988544);   // [256][512]
    float* wt3_2  = (float*)(ws + 15512832);   // [512][1024]

    const float r2_1 = (float)(0.2 * 0.2);
    const float r2_2 = (float)(0.4 * 0.4);

    transpose_all<<<3126, 256, 0, stream>>>(
        s1w0, wt1_0, s1w1, wt1_1, s1w2, wt1_2,
        s2w0, wt2_0, s2w1, wt2_1, s2w2, wt2_2,
        s3w0, wt3_0, s3w1, wt3_1, s3w2, wt3_2);

    fps_fused<4096, 512, 128, 256><<<BATCH, 256, 0, stream>>>(x, l1_xyz, l2_xyz);
    ballq_kernel<4096, 512, 32><<<(BATCH*512)/4, 256, 0, stream>>>(x, l1_xyz, idx1, r2_1);
    sa1_fused<<<(BATCH*512*32)/64, 256, 0, stream>>>(x, l1_xyz, idx1,
        wt1_0, s1b0, wt1_1, s1b1, wt1_2, s1b2, l1_pts);
    ballq_kernel<512, 128, 64><<<(BATCH*128)/4, 256, 0, stream>>>(l1_xyz, l2_xyz, idx2, r2_2);
    sa2_fused<<<BATCH*128, 256, 0, stream>>>(l1_xyz, l1_pts, l2_xyz, idx2,
        wt2_0, s2b0, wt2_1, s2b1, wt2_2, s2b2, l2_pts);
    mlp_gemm_kernel<259, 256,  true,  false><<<dim3(32, 4),  256, 0, stream>>>(l2_xyz, l2_pts, wt3_0, s3b0, h1);
    mlp_gemm_kernel<256, 512,  false, false><<<dim3(32, 8),  256, 0, stream>>>(h1, nullptr, wt3_1, s3b1, h2);
    mlp_gemm_kernel<512, 1024, false, true ><<<dim3(32, 16), 256, 0, stream>>>(h2, nullptr, wt3_2, s3b2, pmax);
    fc_kernel<<<(BATCH*1024)/4, 256, 0, stream>>>(pmax, fw, fb, y);
}

// Round 8
// 1087.429 us; speedup vs baseline: 1.0770x; 1.0770x over previous
//
#include <hip/hip_runtime.h>

#ifndef BATCH
#define BATCH 16
#endif

// ---- DPP wave64 reduction helpers (row_shr scan + row_bcast merge) --------
template<int CTRL>
__device__ __forceinline__ float dppmaxf(float v)
{
    const int d = __builtin_amdgcn_update_dpp(__float_as_int(v), __float_as_int(v),
                                              CTRL, 0xf, 0xf, false);
    return fmaxf(v, __int_as_float(d));
}
template<int CTRL>
__device__ __forceinline__ unsigned dppminu(unsigned v)
{
    const unsigned d = (unsigned)__builtin_amdgcn_update_dpp((int)v, (int)v,
                                                             CTRL, 0xf, 0xf, false);
    return (d < v) ? d : v;
}
// full-wave max of v -> wave-uniform result (via lane 63)
__device__ __forceinline__ float wave_max_bcast(float v)
{
    v = dppmaxf<0x111>(v);  // row_shr:1
    v = dppmaxf<0x112>(v);  // row_shr:2
    v = dppmaxf<0x114>(v);  // row_shr:4
    v = dppmaxf<0x118>(v);  // row_shr:8
    v = dppmaxf<0x142>(v);  // row_bcast:15
    v = dppmaxf<0x143>(v);  // row_bcast:31
    return __int_as_float(__builtin_amdgcn_readlane(__float_as_int(v), 63));
}
__device__ __forceinline__ unsigned wave_min_bcast(unsigned v)
{
    v = dppminu<0x111>(v);
    v = dppminu<0x112>(v);
    v = dppminu<0x114>(v);
    v = dppminu<0x118>(v);
    v = dppminu<0x142>(v);
    v = dppminu<0x143>(v);
    return (unsigned)__builtin_amdgcn_readlane((int)v, 63);
}

// ---------------------------------------------------------------------------
// Fused FPS (both stages). One block per batch, BLOCK=256 (1 wave/SIMD).
// R6 selection scheme (DPP reduce + LDS atomicMax into 3-slot rotation, one
// barrier/step) but ZERO global stores inside the step loops: selections are
// buffered in LDS (s2*/o2*) and written to global once at the end. This
// removes the per-step s_waitcnt vmcnt(0) store-drain from wave 0's barrier.
// Bit-exact: contract(off), (dx*dx+dy*dy)+dz*dz, strict-> first-index argmax
// (pk = dist_bits<<32 | ~idx; indices disjoint across waves -> no u64 ties).
// ---------------------------------------------------------------------------
template<int N, int NP1, int NP2, int BLOCK>
__global__ __launch_bounds__(BLOCK)
void fps_fused(const float* __restrict__ xyz,
               float* __restrict__ out1, float* __restrict__ out2)
{
#pragma clang fp contract(off)
    constexpr int P  = N / BLOCK;     // stage-1 points per thread
    constexpr int P2 = NP1 / BLOCK;   // stage-2 points per thread
    __shared__ float sx[N], sy[N], sz[N];
    __shared__ float s2x[NP1], s2y[NP1], s2z[NP1];
    __shared__ float o2x[NP2], o2y[NP2], o2z[NP2];
    __shared__ unsigned long long slot[3];
    const int b = blockIdx.x, t = threadIdx.x;
    const float* xb = xyz + (size_t)b * N * 3;
    float px[P], py[P], pz[P], dist[P];
#pragma unroll
    for (int j = 0; j < P; ++j) {
        const int i = t + j * BLOCK;
        const float x = xb[i*3+0], y = xb[i*3+1], z = xb[i*3+2];
        sx[i] = x; sy[i] = y; sz[i] = z;
        px[j] = x; py[j] = y; pz[j] = z;
        dist[j] = 1e10f;
    }
    if (t < 3) slot[t] = 0ull;
    __syncthreads();
    float fx = sx[0], fy = sy[0], fz = sz[0];
    if (t == 0) { s2x[0] = fx; s2y[0] = fy; s2z[0] = fz; }
    int cur = 1;                       // slot index = s mod 3, tracked by rotation
    for (int s = 1; s < NP1; ++s) {
        float bestv = -1.f; int besti = 0;
#pragma unroll
        for (int j = 0; j < P; ++j) {
            const float dx = px[j]-fx, dy = py[j]-fy, dz = pz[j]-fz;
            const float d = (dx*dx + dy*dy) + dz*dz;
            const float nd = fminf(dist[j], d);
            dist[j] = nd;
            if (nd > bestv) { bestv = nd; besti = t + j * BLOCK; }  // first idx kept
        }
        const float wm = wave_max_bcast(bestv);
        const unsigned cand = (bestv == wm) ? (unsigned)besti : 0xffffffffu;
        const unsigned wi = wave_min_bcast(cand);
        if ((t & 63) == 0) {
            const unsigned long long pk =
                ((unsigned long long)__float_as_uint(wm) << 32) | (unsigned)(~wi);
            atomicMax(&slot[cur], pk);
        }
        const int nxt = (cur == 2) ? 0 : cur + 1;
        if (t == 0) slot[nxt] = 0ull;   // safe: last read 2 steps ago (barrier between)
        __syncthreads();
        const int far = (int)(~(unsigned)slot[cur]);
        fx = sx[far]; fy = sy[far]; fz = sz[far];
        if (t == 0) { s2x[s] = fx; s2y[s] = fy; s2z[s] = fz; }   // LDS only
        cur = nxt;
    }
    __syncthreads();             // s2 arrays complete
    if (t < 3) slot[t] = 0ull;   // clear rotation for stage 2
    __syncthreads();
    // -------- stage 2: FPS over NP1 sampled points (P2 per thread) ----------
    float mx[P2], my[P2], mz[P2], d2[P2];
#pragma unroll
    for (int j = 0; j < P2; ++j) {
        const int i = t + j * BLOCK;
        mx[j] = s2x[i]; my[j] = s2y[i]; mz[j] = s2z[i];
        d2[j] = 1e10f;
    }
    fx = s2x[0]; fy = s2y[0]; fz = s2z[0];
    if (t == 0) { o2x[0] = fx; o2y[0] = fy; o2z[0] = fz; }
    cur = 1;
    for (int s = 1; s < NP2; ++s) {
        float bestv = -1.f; int besti = 0;
#pragma unroll
        for (int j = 0; j < P2; ++j) {
            const float dx = mx[j]-fx, dy = my[j]-fy, dz = mz[j]-fz;
            const float d = (dx*dx + dy*dy) + dz*dz;
            const float nd = fminf(d2[j], d);
            d2[j] = nd;
            if (nd > bestv) { bestv = nd; besti = t + j * BLOCK; }
        }
        const float wm = wave_max_bcast(bestv);
        const unsigned cand = (bestv == wm) ? (unsigned)besti : 0xffffffffu;
        const unsigned wi = wave_min_bcast(cand);
        if ((t & 63) == 0) {
            const unsigned long long pk =
                ((unsigned long long)__float_as_uint(wm) << 32) | (unsigned)(~wi);
            atomicMax(&slot[cur], pk);
        }
        const int nxt = (cur == 2) ? 0 : cur + 1;
        if (t == 0) slot[nxt] = 0ull;
        __syncthreads();
        const int far2 = (int)(~(unsigned)slot[cur]);
        fx = s2x[far2]; fy = s2y[far2]; fz = s2z[far2];
        if (t == 0) { o2x[s] = fx; o2y[s] = fy; o2z[s] = fz; }   // LDS only
        cur = nxt;
    }
    __syncthreads();             // o2 complete
    // -------- one-time global writes (off the serial path) ------------------
    for (int i = t; i < NP1; i += BLOCK) {
        out1[((size_t)b*NP1 + i)*3 + 0] = s2x[i];
        out1[((size_t)b*NP1 + i)*3 + 1] = s2y[i];
        out1[((size_t)b*NP1 + i)*3 + 2] = s2z[i];
    }
    for (int i = t; i < NP2; i += BLOCK) {
        out2[((size_t)b*NP2 + i)*3 + 0] = o2x[i];
        out2[((size_t)b*NP2 + i)*3 + 1] = o2y[i];
        out2[((size_t)b*NP2 + i)*3 + 2] = o2z[i];
    }
}

// ---------------------------------------------------------------------------
// Ball query (unchanged, known-correct)
// ---------------------------------------------------------------------------
template<int N, int S, int K>
__global__ __launch_bounds__(256)
void ballq_kernel(const float* __restrict__ xyz, const float* __restrict__ nxyz,
                  int* __restrict__ idx, const float r2)
{
#pragma clang fp contract(off)
    const int gw = (blockIdx.x * 256 + threadIdx.x) >> 6;
    const int lane = threadIdx.x & 63;
    const int b = gw / S, s = gw % S;
    const float* xb = xyz + (size_t)b * N * 3;
    const float qx = nxyz[((size_t)b*S + s)*3 + 0];
    const float qy = nxyz[((size_t)b*S + s)*3 + 1];
    const float qz = nxyz[((size_t)b*S + s)*3 + 2];
    int* op = idx + ((size_t)b*S + s) * K;
    int base = 0, first = -1;
    for (int c = 0; c < N; c += 64) {
        const int i = c + lane;
        const float dx = xb[i*3+0]-qx, dy = xb[i*3+1]-qy, dz = xb[i*3+2]-qz;
        const float d = (dx*dx + dy*dy) + dz*dz;
        const bool hit = !(d > r2);
        const unsigned long long m = __ballot(hit);
        if (first < 0 && m) first = c + __builtin_ctzll(m);
        const int pos = base + __popcll(m & ((1ull << lane) - 1ull));
        if (hit && pos < K) op[pos] = i;
        base += __popcll(m);
        if (base >= K) break;
    }
    if (base < K && lane >= base && lane < K) op[lane] = first;
}

// ---------------------------------------------------------------------------
// All 9 weight transposes W[O][C] -> Wt[C][O] in one launch.
// ---------------------------------------------------------------------------
__global__ __launch_bounds__(256)
void transpose_all(const float* __restrict__ s0, float* __restrict__ d0,
                   const float* __restrict__ s1, float* __restrict__ d1,
                   const float* __restrict__ s2, float* __restrict__ d2,
                   const float* __restrict__ s3, float* __restrict__ d3,
                   const float* __restrict__ s4, float* __restrict__ d4,
                   const float* __restrict__ s5, float* __restrict__ d5,
                   const float* __restrict__ s6, float* __restrict__ d6,
                   const float* __restrict__ s7, float* __restrict__ d7,
                   const float* __restrict__ s8, float* __restrict__ d8)
{
    int i = blockIdx.x * 256 + threadIdx.x;
    if (i < 192)    { d0[(i%3)  *64   + i/3  ] = s0[i]; return; }  i -= 192;
    if (i < 4096)   { d1[(i&63) *64   + (i>>6)] = s1[i]; return; } i -= 4096;
    if (i < 8192)   { d2[(i&63) *128  + (i>>6)] = s2[i]; return; } i -= 8192;
    if (i < 16768)  { d3[(i%131)*128  + i/131] = s3[i]; return; }  i -= 16768;
    if (i < 16384)  { d4[(i&127)*128  + (i>>7)] = s4[i]; return; } i -= 16384;
    if (i < 32768)  { d5[(i&127)*256  + (i>>7)] = s5[i]; return; } i -= 32768;
    if (i < 66304)  { d6[(i%259)*256  + i/259] = s6[i]; return; }  i -= 66304;
    if (i < 131072) { d7[(i&255)*512  + (i>>8)] = s7[i]; return; } i -= 131072;
    if (i < 524288) { d8[(i&511)*1024 + (i>>9)] = s8[i]; return; }
}

// 16 FMAs against 16 contiguous transposed weights (4x float4, 16B-aligned)
__device__ __forceinline__ void fma16(float (&acc)[16], const float f,
                                      const float* __restrict__ wrow)
{
    const float4 w0 = ((const float4*)wrow)[0];
    const float4 w1 = ((const float4*)wrow)[1];
    const float4 w2 = ((const float4*)wrow)[2];
    const float4 w3 = ((const float4*)wrow)[3];
    acc[0]+=f*w0.x;  acc[1]+=f*w0.y;  acc[2]+=f*w0.z;  acc[3]+=f*w0.w;
    acc[4]+=f*w1.x;  acc[5]+=f*w1.y;  acc[6]+=f*w1.z;  acc[7]+=f*w1.w;
    acc[8]+=f*w2.x;  acc[9]+=f*w2.y;  acc[10]+=f*w2.z; acc[11]+=f*w2.w;
    acc[12]+=f*w3.x; acc[13]+=f*w3.y; acc[14]+=f*w3.z; acc[15]+=f*w3.w;
}

// ---------------------------------------------------------------------------
// SA1 fused (unchanged)
// ---------------------------------------------------------------------------
__global__ __launch_bounds__(256)
void sa1_fused(const float* __restrict__ xyz, const float* __restrict__ nxyz,
               const int* __restrict__ idx,
               const float* __restrict__ Wt0, const float* __restrict__ B0,
               const float* __restrict__ Wt1, const float* __restrict__ B1,
               const float* __restrict__ Wt2, const float* __restrict__ B2,
               float* __restrict__ out)
{
    __shared__ float h1S[64][64];
    __shared__ float h2S[64][64];
    const int tid = threadIdx.x, lane = tid & 63;
    const int wave = __builtin_amdgcn_readfirstlane(tid >> 6);
    const int row0 = blockIdx.x * 64;
    const int myrow = row0 + lane;
    const int g = myrow >> 5, b = g >> 9;
    const int i = idx[myrow];
    const float* p = xyz + ((size_t)b*4096 + i) * 3;
    const float f0 = p[0] - nxyz[(size_t)g*3 + 0];
    const float f1 = p[1] - nxyz[(size_t)g*3 + 1];
    const float f2 = p[2] - nxyz[(size_t)g*3 + 2];
    const int oc0 = wave * 16;
    float acc[16];
#pragma unroll
    for (int j = 0; j < 16; ++j)
        acc[j] = B0[oc0+j] + f0*Wt0[0*64+oc0+j] + f1*Wt0[1*64+oc0+j] + f2*Wt0[2*64+oc0+j];
#pragma unroll
    for (int j = 0; j < 16; ++j) h1S[oc0+j][lane] = fmaxf(acc[j], 0.f);
    __syncthreads();
#pragma unroll
    for (int j = 0; j < 16; ++j) acc[j] = B1[oc0+j];
#pragma unroll 4
    for (int ci = 0; ci < 64; ++ci)
        fma16(acc, h1S[ci][lane], Wt1 + ci*64 + oc0);
#pragma unroll
    for (int j = 0; j < 16; ++j) h2S[oc0+j][lane] = fmaxf(acc[j], 0.f);
    __syncthreads();
    for (int pass = 0; pass < 2; ++pass) {
        const int oc = pass*64 + oc0;
#pragma unroll
        for (int j = 0; j < 16; ++j) acc[j] = B2[oc+j];
#pragma unroll 4
        for (int ci = 0; ci < 64; ++ci)
            fma16(acc, h2S[ci][lane], Wt2 + ci*128 + oc);
#pragma unroll
        for (int j = 0; j < 16; ++j) {
            float v = fmaxf(acc[j], 0.f);
            v = fmaxf(v, __shfl_xor(v, 1));
            v = fmaxf(v, __shfl_xor(v, 2));
            v = fmaxf(v, __shfl_xor(v, 4));
            v = fmaxf(v, __shfl_xor(v, 8));
            v = fmaxf(v, __shfl_xor(v, 16));
            if ((lane & 31) == 0)
                out[(size_t)((row0 + lane) >> 5) * 128 + oc + j] = v;
        }
    }
}

// ---------------------------------------------------------------------------
// SA2 fused (unchanged)
// ---------------------------------------------------------------------------
__global__ __launch_bounds__(256)
void sa2_fused(const float* __restrict__ l1xyz, const float* __restrict__ l1pts,
               const float* __restrict__ nxyz, const int* __restrict__ idx,
               const float* __restrict__ Wt0, const float* __restrict__ B0,
               const float* __restrict__ Wt1, const float* __restrict__ B1,
               const float* __restrict__ Wt2, const float* __restrict__ B2,
               float* __restrict__ out)
{
    __shared__ float featS[128][64];
    __shared__ float hS[128][64];
    const int tid = threadIdx.x, lane = tid & 63;
    const int wave = __builtin_amdgcn_readfirstlane(tid >> 6);
    const int gblk = blockIdx.x;
    const int b = gblk >> 7;
    const int row0 = gblk * 64;
    const int myi = idx[row0 + lane];
    const float* pc = l1xyz + ((size_t)b*512 + myi) * 3;
    const float f0 = pc[0] - nxyz[(size_t)gblk*3 + 0];
    const float f1 = pc[1] - nxyz[(size_t)gblk*3 + 1];
    const float f2 = pc[2] - nxyz[(size_t)gblk*3 + 2];
    for (int r = wave; r < 64; r += 4) {
        const int i2 = idx[row0 + r];
        const float* src = l1pts + ((size_t)b*512 + i2) * 128;
        featS[lane][r ^ lane]    = src[lane];
        featS[lane+64][r ^ lane] = src[lane + 64];
    }
    __syncthreads();
    const int oc0 = wave * 16;
    float acc[16];
    for (int pass = 0; pass < 2; ++pass) {
        const int oc = pass*64 + oc0;
#pragma unroll
        for (int j = 0; j < 16; ++j)
            acc[j] = B0[oc+j] + f0*Wt0[0*128+oc+j] + f1*Wt0[1*128+oc+j] + f2*Wt0[2*128+oc+j];
#pragma unroll 4
        for (int ci = 0; ci < 128; ++ci)
            fma16(acc, featS[ci][lane ^ (ci & 63)], Wt0 + (size_t)(ci+3)*128 + oc);
#pragma unroll
        for (int j = 0; j < 16; ++j) hS[oc+j][lane] = fmaxf(acc[j], 0.f);
    }
    __syncthreads();
    for (int pass = 0; pass < 2; ++pass) {
        const int oc = pass*64 + oc0;
#pragma unroll
        for (int j = 0; j < 16; ++j) acc[j] = B1[oc+j];
#pragma unroll 4
        for (int ci = 0; ci < 128; ++ci)
            fma16(acc, hS[ci][lane], Wt1 + (size_t)ci*128 + oc);
#pragma unroll
        for (int j = 0; j < 16; ++j) featS[oc+j][lane] = fmaxf(acc[j], 0.f);
    }
    __syncthreads();
    float* orow = out + (size_t)gblk * 256;
    for (int pass = 0; pass < 4; ++pass) {
        const int oc = pass*64 + oc0;
#pragma unroll
        for (int j = 0; j < 16; ++j) acc[j] = B2[oc+j];
#pragma unroll 4
        for (int ci = 0; ci < 128; ++ci)
            fma16(acc, featS[ci][lane], Wt2 + (size_t)ci*256 + oc);
#pragma unroll
        for (int j = 0; j < 16; ++j) {
            float v = fmaxf(acc[j], 0.f);
            v = fmaxf(v, __shfl_xor(v, 1));
            v = fmaxf(v, __shfl_xor(v, 2));
            v = fmaxf(v, __shfl_xor(v, 4));
            v = fmaxf(v, __shfl_xor(v, 8));
            v = fmaxf(v, __shfl_xor(v, 16));
            v = fmaxf(v, __shfl_xor(v, 32));
            if (lane == 0) orow[oc + j] = v;
        }
    }
}

// ---------------------------------------------------------------------------
// SA3 GEMM layers (unchanged)
// ---------------------------------------------------------------------------
template<int CIN, int COUT, bool CONCAT3, bool POOL>
__global__ __launch_bounds__(256)
void mlp_gemm_kernel(const float* __restrict__ inA, const float* __restrict__ inB,
                     const float* __restrict__ Wt, const float* __restrict__ Bb,
                     float* __restrict__ out)
{
    __shared__ float featS[128][64];
    const int tid = threadIdx.x, lane = tid & 63;
    const int wave = __builtin_amdgcn_readfirstlane(tid >> 6);
    const int row0 = blockIdx.x * 64;
    const int oc0 = blockIdx.y * 64 + wave * 16;
    float acc[16];
#pragma unroll
    for (int j = 0; j < 16; ++j) acc[j] = Bb[oc0 + j];
    for (int c0 = 0; c0 < CIN; c0 += 128) {
        const int csz = (CIN - c0 < 128) ? (CIN - c0) : 128;
        __syncthreads();
        for (int r = wave; r < 64; r += 4) {
            const int row = row0 + r;
            for (int cl = lane; cl < csz; cl += 64) {
                const int cig = c0 + cl;
                float v;
                if (CONCAT3)
                    v = (cig < 3) ? inA[(size_t)row*3 + cig]
                                  : inB[(size_t)row*(CIN-3) + (cig - 3)];
                else
                    v = inA[(size_t)row*CIN + cig];
                featS[cl][r ^ (cl & 63)] = v;
            }
        }
        __syncthreads();
        if (csz == 128) {
#pragma unroll 4
            for (int ci = 0; ci < 128; ++ci)
                fma16(acc, featS[ci][lane ^ (ci & 63)], Wt + (size_t)(c0+ci)*COUT + oc0);
        } else {
            for (int ci = 0; ci < csz; ++ci)
                fma16(acc, featS[ci][lane ^ (ci & 63)], Wt + (size_t)(c0+ci)*COUT + oc0);
        }
    }
    if (POOL) {
#pragma unroll
        for (int j = 0; j < 16; ++j) {
            float v = fmaxf(acc[j], 0.f);
            v = fmaxf(v, __shfl_xor(v, 1));
            v = fmaxf(v, __shfl_xor(v, 2));
            v = fmaxf(v, __shfl_xor(v, 4));
            v = fmaxf(v, __shfl_xor(v, 8));
            v = fmaxf(v, __shfl_xor(v, 16));
            v = fmaxf(v, __shfl_xor(v, 32));
            if (lane == 0) out[(size_t)blockIdx.x * COUT + oc0 + j] = v;
        }
    } else {
        float4 o0, o1, o2, o3;
        o0.x=fmaxf(acc[0],0.f);  o0.y=fmaxf(acc[1],0.f);  o0.z=fmaxf(acc[2],0.f);  o0.w=fmaxf(acc[3],0.f);
        o1.x=fmaxf(acc[4],0.f);  o1.y=fmaxf(acc[5],0.f);  o1.z=fmaxf(acc[6],0.f);  o1.w=fmaxf(acc[7],0.f);
        o2.x=fmaxf(acc[8],0.f);  o2.y=fmaxf(acc[9],0.f);  o2.z=fmaxf(acc[10],0.f); o2.w=fmaxf(acc[11],0.f);
        o3.x=fmaxf(acc[12],0.f); o3.y=fmaxf(acc[13],0.f); o3.z=fmaxf(acc[14],0.f); o3.w=fmaxf(acc[15],0.f);
        float4* op = (float4*)(out + (size_t)(row0 + lane)*COUT + oc0);
        op[0]=o0; op[1]=o1; op[2]=o2; op[3]=o3;
    }
}

// y[b][o] = fb[o] + max(pmax[2b], pmax[2b+1]) . fw[o]; one wave per output
__global__ __launch_bounds__(256)
void fc_kernel(const float* __restrict__ pmax, const float* __restrict__ fw,
               const float* __restrict__ fb, float* __restrict__ y)
{
    const int gw = (blockIdx.x * 256 + threadIdx.x) >> 6;
    const int lane = threadIdx.x & 63;
    const int b = gw >> 10, o = gw & 1023;
    const float4* g0 = (const float4*)(pmax + (size_t)(2*b) * 1024);
    const float4* g1 = (const float4*)(pmax + (size_t)(2*b+1) * 1024);
    const float4* wv = (const float4*)(fw + (size_t)o * 1024);
    float acc = 0.f;
#pragma unroll
    for (int r = 0; r < 4; ++r) {
        const float4 a = g0[lane + r*64];
        const float4 c = g1[lane + r*64];
        const float4 w = wv[lane + r*64];
        acc += fmaxf(a.x,c.x)*w.x + fmaxf(a.y,c.y)*w.y
             + fmaxf(a.z,c.z)*w.z + fmaxf(a.w,c.w)*w.w;
    }
#pragma unroll
    for (int m = 32; m >= 1; m >>= 1) acc += __shfl_xor(acc, m);
    if (lane == 0) y[gw] = acc + fb[o];
}

extern "C" void kernel_launch(void* const* d_in, const int* in_sizes, int n_in,
                              void* d_out, int out_size, void* d_ws, size_t ws_size,
                              hipStream_t stream)
{
    (void)in_sizes; (void)n_in; (void)out_size; (void)ws_size;
    const float* x   = (const float*)d_in[0];
    const float* s1w0 = (const float*)d_in[1];  const float* s1b0 = (const float*)d_in[2];
    const float* s1w1 = (const float*)d_in[3];  const float* s1b1 = (const float*)d_in[4];
    const float* s1w2 = (const float*)d_in[5];  const float* s1b2 = (const float*)d_in[6];
    const float* s2w0 = (const float*)d_in[7];  const float* s2b0 = (const float*)d_in[8];
    const float* s2w1 = (const float*)d_in[9];  const float* s2b1 = (const float*)d_in[10];
    const float* s2w2 = (const float*)d_in[11]; const float* s2b2 = (const float*)d_in[12];
    const float* s3w0 = (const float*)d_in[13]; const float* s3b0 = (const float*)d_in[14];
    const float* s3w1 = (const float*)d_in[15]; const float* s3b1 = (const float*)d_in[16];
    const float* s3w2 = (const float*)d_in[17]; const float* s3b2 = (const float*)d_in[18];
    const float* fw  = (const float*)d_in[19]; const float* fb  = (const float*)d_in[20];
    float* y = (float*)d_out;

    char* ws = (char*)d_ws;
    float* l1_xyz = (float*)(ws + 0);          // 16*512*3
    int*   idx1   = (int*)  (ws + 98304);      // 16*512*32
    float* l1_pts = (float*)(ws + 1146880);    // 16*512*128
    float* l2_xyz = (float*)(ws + 5341184);    // 16*128*3
    int*   idx2   = (int*)  (ws + 5365760);    // 16*128*64
    float* l2_pts = (float*)(ws + 5890048);    // 16*128*256
    float* h1     = (float*)(ws + 7987200);    // 2048*256
    float* h2     = (float*)(ws + 10084352);   // 2048*512
    float* pmax   = (float*)(ws + 14278656);   // 32*1024 partial maxes
    float* wt1_0  = (float*)(ws + 14409728);   // [3][64]
    float* wt1_1  = (float*)(ws + 14410496);   // [64][64]
    float* wt1_2  = (float*)(ws + 14426880);   // [64][128]
    float* wt2_0  = (float*)(ws + 14459648);   // [131][128]
    float* wt2_1  = (float*)(ws + 14526720);   // [128][128]
    float* wt2_2  = (float*)(ws + 14592256);   // [128][256]
    float* wt3_0  = (float*)(ws + 14723328);   // [259][256]
    float* wt3_1  = (float*)(ws + 14988544);   // [256][512]
    float* wt3_2  = (float*)(ws + 15512832);   // [512][1024]

    const float r2_1 = (float)(0.2 * 0.2);
    const float r2_2 = (float)(0.4 * 0.4);

    transpose_all<<<3126, 256, 0, stream>>>(
        s1w0, wt1_0, s1w1, wt1_1, s1w2, wt1_2,
        s2w0, wt2_0, s2w1, wt2_1, s2w2, wt2_2,
        s3w0, wt3_0, s3w1, wt3_1, s3w2, wt3_2);

    fps_fused<4096, 512, 128, 256><<<BATCH, 256, 0, stream>>>(x, l1_xyz, l2_xyz);
    ballq_kernel<4096, 512, 32><<<(BATCH*512)/4, 256, 0, stream>>>(x, l1_xyz, idx1, r2_1);
    sa1_fused<<<(BATCH*512*32)/64, 256, 0, stream>>>(x, l1_xyz, idx1,
        wt1_0, s1b0, wt1_1, s1b1, wt1_2, s1b2, l1_pts);
    ballq_kernel<512, 128, 64><<<(BATCH*128)/4, 256, 0, stream>>>(l1_xyz, l2_xyz, idx2, r2_2);
    sa2_fused<<<BATCH*128, 256, 0, stream>>>(l1_xyz, l1_pts, l2_xyz, idx2,
        wt2_0, s2b0, wt2_1, s2b1, wt2_2, s2b2, l2_pts);
    mlp_gemm_kernel<259, 256,  true,  false><<<dim3(32, 4),  256, 0, stream>>>(l2_xyz, l2_pts, wt3_0, s3b0, h1);
    mlp_gemm_kernel<256, 512,  false, false><<<dim3(32, 8),  256, 0, stream>>>(h1, nullptr, wt3_1, s3b1, h2);
    mlp_gemm_kernel<512, 1024, false, true ><<<dim3(32, 16), 256, 0, stream>>>(h2, nullptr, wt3_2, s3b2, pmax);
    fc_kernel<<<(BATCH*1024)/4, 256, 0, stream>>>(pmax, fw, fb, y);
}

// Round 9
// 947.993 us; speedup vs baseline: 1.2354x; 1.1471x over previous
//
#include <hip/hip_runtime.h>

#ifndef BATCH
#define BATCH 16
#endif

// ---- DPP wave64 reduction helpers (row_shr scan + row_bcast merge) --------
template<int CTRL>
__device__ __forceinline__ float dppmaxf(float v)
{
    const int d = __builtin_amdgcn_update_dpp(__float_as_int(v), __float_as_int(v),
                                              CTRL, 0xf, 0xf, false);
    return fmaxf(v, __int_as_float(d));
}
template<int CTRL>
__device__ __forceinline__ unsigned dppminu(unsigned v)
{
    const unsigned d = (unsigned)__builtin_amdgcn_update_dpp((int)v, (int)v,
                                                             CTRL, 0xf, 0xf, false);
    return (d < v) ? d : v;
}
// full-wave max of v -> wave-uniform result (via lane 63)
__device__ __forceinline__ float wave_max_bcast(float v)
{
    v = dppmaxf<0x111>(v);  // row_shr:1
    v = dppmaxf<0x112>(v);  // row_shr:2
    v = dppmaxf<0x114>(v);  // row_shr:4
    v = dppmaxf<0x118>(v);  // row_shr:8
    v = dppmaxf<0x142>(v);  // row_bcast:15
    v = dppmaxf<0x143>(v);  // row_bcast:31
    return __int_as_float(__builtin_amdgcn_readlane(__float_as_int(v), 63));
}
__device__ __forceinline__ unsigned wave_min_bcast(unsigned v)
{
    v = dppminu<0x111>(v);
    v = dppminu<0x112>(v);
    v = dppminu<0x114>(v);
    v = dppminu<0x118>(v);
    v = dppminu<0x142>(v);
    v = dppminu<0x143>(v);
    return (unsigned)__builtin_amdgcn_readlane((int)v, 63);
}

// ---------------------------------------------------------------------------
// Fused FPS (both stages). Unchanged from R8 (best known: ~377 us).
// ---------------------------------------------------------------------------
template<int N, int NP1, int NP2, int BLOCK>
__global__ __launch_bounds__(BLOCK)
void fps_fused(const float* __restrict__ xyz,
               float* __restrict__ out1, float* __restrict__ out2)
{
#pragma clang fp contract(off)
    constexpr int P  = N / BLOCK;
    constexpr int P2 = NP1 / BLOCK;
    __shared__ float sx[N], sy[N], sz[N];
    __shared__ float s2x[NP1], s2y[NP1], s2z[NP1];
    __shared__ float o2x[NP2], o2y[NP2], o2z[NP2];
    __shared__ unsigned long long slot[3];
    const int b = blockIdx.x, t = threadIdx.x;
    const float* xb = xyz + (size_t)b * N * 3;
    float px[P], py[P], pz[P], dist[P];
#pragma unroll
    for (int j = 0; j < P; ++j) {
        const int i = t + j * BLOCK;
        const float x = xb[i*3+0], y = xb[i*3+1], z = xb[i*3+2];
        sx[i] = x; sy[i] = y; sz[i] = z;
        px[j] = x; py[j] = y; pz[j] = z;
        dist[j] = 1e10f;
    }
    if (t < 3) slot[t] = 0ull;
    __syncthreads();
    float fx = sx[0], fy = sy[0], fz = sz[0];
    if (t == 0) { s2x[0] = fx; s2y[0] = fy; s2z[0] = fz; }
    int cur = 1;
    for (int s = 1; s < NP1; ++s) {
        float bestv = -1.f; int besti = 0;
#pragma unroll
        for (int j = 0; j < P; ++j) {
            const float dx = px[j]-fx, dy = py[j]-fy, dz = pz[j]-fz;
            const float d = (dx*dx + dy*dy) + dz*dz;
            const float nd = fminf(dist[j], d);
            dist[j] = nd;
            if (nd > bestv) { bestv = nd; besti = t + j * BLOCK; }
        }
        const float wm = wave_max_bcast(bestv);
        const unsigned cand = (bestv == wm) ? (unsigned)besti : 0xffffffffu;
        const unsigned wi = wave_min_bcast(cand);
        if ((t & 63) == 0) {
            const unsigned long long pk =
                ((unsigned long long)__float_as_uint(wm) << 32) | (unsigned)(~wi);
            atomicMax(&slot[cur], pk);
        }
        const int nxt = (cur == 2) ? 0 : cur + 1;
        if (t == 0) slot[nxt] = 0ull;
        __syncthreads();
        const int far = (int)(~(unsigned)slot[cur]);
        fx = sx[far]; fy = sy[far]; fz = sz[far];
        if (t == 0) { s2x[s] = fx; s2y[s] = fy; s2z[s] = fz; }
        cur = nxt;
    }
    __syncthreads();
    if (t < 3) slot[t] = 0ull;
    __syncthreads();
    float mx[P2], my[P2], mz[P2], d2[P2];
#pragma unroll
    for (int j = 0; j < P2; ++j) {
        const int i = t + j * BLOCK;
        mx[j] = s2x[i]; my[j] = s2y[i]; mz[j] = s2z[i];
        d2[j] = 1e10f;
    }
    fx = s2x[0]; fy = s2y[0]; fz = s2z[0];
    if (t == 0) { o2x[0] = fx; o2y[0] = fy; o2z[0] = fz; }
    cur = 1;
    for (int s = 1; s < NP2; ++s) {
        float bestv = -1.f; int besti = 0;
#pragma unroll
        for (int j = 0; j < P2; ++j) {
            const float dx = mx[j]-fx, dy = my[j]-fy, dz = mz[j]-fz;
            const float d = (dx*dx + dy*dy) + dz*dz;
            const float nd = fminf(d2[j], d);
            d2[j] = nd;
            if (nd > bestv) { bestv = nd; besti = t + j * BLOCK; }
        }
        const float wm = wave_max_bcast(bestv);
        const unsigned cand = (bestv == wm) ? (unsigned)besti : 0xffffffffu;
        const unsigned wi = wave_min_bcast(cand);
        if ((t & 63) == 0) {
            const unsigned long long pk =
                ((unsigned long long)__float_as_uint(wm) << 32) | (unsigned)(~wi);
            atomicMax(&slot[cur], pk);
        }
        const int nxt = (cur == 2) ? 0 : cur + 1;
        if (t == 0) slot[nxt] = 0ull;
        __syncthreads();
        const int far2 = (int)(~(unsigned)slot[cur]);
        fx = s2x[far2]; fy = s2y[far2]; fz = s2z[far2];
        if (t == 0) { o2x[s] = fx; o2y[s] = fy; o2z[s] = fz; }
        cur = nxt;
    }
    __syncthreads();
    for (int i = t; i < NP1; i += BLOCK) {
        out1[((size_t)b*NP1 + i)*3 + 0] = s2x[i];
        out1[((size_t)b*NP1 + i)*3 + 1] = s2y[i];
        out1[((size_t)b*NP1 + i)*3 + 2] = s2z[i];
    }
    for (int i = t; i < NP2; i += BLOCK) {
        out2[((size_t)b*NP2 + i)*3 + 0] = o2x[i];
        out2[((size_t)b*NP2 + i)*3 + 1] = o2y[i];
        out2[((size_t)b*NP2 + i)*3 + 2] = o2z[i];
    }
}

// ---------------------------------------------------------------------------
// Ball query (unchanged, known-correct)
// ---------------------------------------------------------------------------
template<int N, int S, int K>
__global__ __launch_bounds__(256)
void ballq_kernel(const float* __restrict__ xyz, const float* __restrict__ nxyz,
                  int* __restrict__ idx, const float r2)
{
#pragma clang fp contract(off)
    const int gw = (blockIdx.x * 256 + threadIdx.x) >> 6;
    const int lane = threadIdx.x & 63;
    const int b = gw / S, s = gw % S;
    const float* xb = xyz + (size_t)b * N * 3;
    const float qx = nxyz[((size_t)b*S + s)*3 + 0];
    const float qy = nxyz[((size_t)b*S + s)*3 + 1];
    const float qz = nxyz[((size_t)b*S + s)*3 + 2];
    int* op = idx + ((size_t)b*S + s) * K;
    int base = 0, first = -1;
    for (int c = 0; c < N; c += 64) {
        const int i = c + lane;
        const float dx = xb[i*3+0]-qx, dy = xb[i*3+1]-qy, dz = xb[i*3+2]-qz;
        const float d = (dx*dx + dy*dy) + dz*dz;
        const bool hit = !(d > r2);
        const unsigned long long m = __ballot(hit);
        if (first < 0 && m) first = c + __builtin_ctzll(m);
        const int pos = base + __popcll(m & ((1ull << lane) - 1ull));
        if (hit && pos < K) op[pos] = i;
        base += __popcll(m);
        if (base >= K) break;
    }
    if (base < K && lane >= base && lane < K) op[lane] = first;
}

// ---------------------------------------------------------------------------
// All 9 weight transposes W[O][C] -> Wt[C][O] in one launch.
// ---------------------------------------------------------------------------
__global__ __launch_bounds__(256)
void transpose_all(const float* __restrict__ s0, float* __restrict__ d0,
                   const float* __restrict__ s1, float* __restrict__ d1,
                   const float* __restrict__ s2, float* __restrict__ d2,
                   const float* __restrict__ s3, float* __restrict__ d3,
                   const float* __restrict__ s4, float* __restrict__ d4,
                   const float* __restrict__ s5, float* __restrict__ d5,
                   const float* __restrict__ s6, float* __restrict__ d6,
                   const float* __restrict__ s7, float* __restrict__ d7,
                   const float* __restrict__ s8, float* __restrict__ d8)
{
    int i = blockIdx.x * 256 + threadIdx.x;
    if (i < 192)    { d0[(i%3)  *64   + i/3  ] = s0[i]; return; }  i -= 192;
    if (i < 4096)   { d1[(i&63) *64   + (i>>6)] = s1[i]; return; } i -= 4096;
    if (i < 8192)   { d2[(i&63) *128  + (i>>6)] = s2[i]; return; } i -= 8192;
    if (i < 16768)  { d3[(i%131)*128  + i/131] = s3[i]; return; }  i -= 16768;
    if (i < 16384)  { d4[(i&127)*128  + (i>>7)] = s4[i]; return; } i -= 16384;
    if (i < 32768)  { d5[(i&127)*256  + (i>>7)] = s5[i]; return; } i -= 32768;
    if (i < 66304)  { d6[(i%259)*256  + i/259] = s6[i]; return; }  i -= 66304;
    if (i < 131072) { d7[(i&255)*512  + (i>>8)] = s7[i]; return; } i -= 131072;
    if (i < 524288) { d8[(i&511)*1024 + (i>>9)] = s8[i]; return; }
}

// 16 FMAs against 16 contiguous transposed weights (4x float4, 16B-aligned)
__device__ __forceinline__ void fma16(float (&acc)[16], const float f,
                                      const float* __restrict__ wrow)
{
    const float4 w0 = ((const float4*)wrow)[0];
    const float4 w1 = ((const float4*)wrow)[1];
    const float4 w2 = ((const float4*)wrow)[2];
    const float4 w3 = ((const float4*)wrow)[3];
    acc[0]+=f*w0.x;  acc[1]+=f*w0.y;  acc[2]+=f*w0.z;  acc[3]+=f*w0.w;
    acc[4]+=f*w1.x;  acc[5]+=f*w1.y;  acc[6]+=f*w1.z;  acc[7]+=f*w1.w;
    acc[8]+=f*w2.x;  acc[9]+=f*w2.y;  acc[10]+=f*w2.z; acc[11]+=f*w2.w;
    acc[12]+=f*w3.x; acc[13]+=f*w3.y; acc[14]+=f*w3.z; acc[15]+=f*w3.w;
}

// ---------------------------------------------------------------------------
// SA1 fused, in-place single 16 KB buffer: gather-free L1 (inputs in regs),
// each layer accumulates in registers then overwrites the buffer after a
// barrier. Per-oc accumulation order identical to R8 -> bit-identical.
// ---------------------------------------------------------------------------
__global__ __launch_bounds__(256)
void sa1_fused(const float* __restrict__ xyz, const float* __restrict__ nxyz,
               const int* __restrict__ idx,
               const float* __restrict__ Wt0, const float* __restrict__ B0,
               const float* __restrict__ Wt1, const float* __restrict__ B1,
               const float* __restrict__ Wt2, const float* __restrict__ B2,
               float* __restrict__ out)
{
    __shared__ float buf[64][64];    // 16 KB: h1, then h2 (in-place)
    const int tid = threadIdx.x, lane = tid & 63;
    const int wave = __builtin_amdgcn_readfirstlane(tid >> 6);
    const int row0 = blockIdx.x * 64;
    const int myrow = row0 + lane;
    const int g = myrow >> 5, b = g >> 9;
    const int i = idx[myrow];
    const float* p = xyz + ((size_t)b*4096 + i) * 3;
    const float f0 = p[0] - nxyz[(size_t)g*3 + 0];
    const float f1 = p[1] - nxyz[(size_t)g*3 + 1];
    const float f2 = p[2] - nxyz[(size_t)g*3 + 2];
    const int oc0 = wave * 16;
    float aL[16], aH[16];
    // L1: 3 -> 64 (no LDS input)
#pragma unroll
    for (int j = 0; j < 16; ++j)
        aL[j] = B0[oc0+j] + f0*Wt0[0*64+oc0+j] + f1*Wt0[1*64+oc0+j] + f2*Wt0[2*64+oc0+j];
#pragma unroll
    for (int j = 0; j < 16; ++j) buf[oc0+j][lane] = fmaxf(aL[j], 0.f);
    __syncthreads();
    // L2: 64 -> 64 (read all, barrier, overwrite in place)
#pragma unroll
    for (int j = 0; j < 16; ++j) aL[j] = B1[oc0+j];
#pragma unroll 4
    for (int ci = 0; ci < 64; ++ci)
        fma16(aL, buf[ci][lane], Wt1 + ci*64 + oc0);
    __syncthreads();
#pragma unroll
    for (int j = 0; j < 16; ++j) buf[oc0+j][lane] = fmaxf(aL[j], 0.f);
    __syncthreads();
    // L3: 64 -> 128, both oc-halves in one sweep + maxpool over K=32
#pragma unroll
    for (int j = 0; j < 16; ++j) { aL[j] = B2[oc0+j]; aH[j] = B2[64+oc0+j]; }
#pragma unroll 2
    for (int ci = 0; ci < 64; ++ci) {
        const float f = buf[ci][lane];
        fma16(aL, f, Wt2 + ci*128 + oc0);
        fma16(aH, f, Wt2 + ci*128 + 64 + oc0);
    }
#pragma unroll
    for (int j = 0; j < 16; ++j) {
        float v = fmaxf(aL[j], 0.f);
        v = fmaxf(v, __shfl_xor(v, 1));
        v = fmaxf(v, __shfl_xor(v, 2));
        v = fmaxf(v, __shfl_xor(v, 4));
        v = fmaxf(v, __shfl_xor(v, 8));
        v = fmaxf(v, __shfl_xor(v, 16));
        float w = fmaxf(aH[j], 0.f);
        w = fmaxf(w, __shfl_xor(w, 1));
        w = fmaxf(w, __shfl_xor(w, 2));
        w = fmaxf(w, __shfl_xor(w, 4));
        w = fmaxf(w, __shfl_xor(w, 8));
        w = fmaxf(w, __shfl_xor(w, 16));
        if ((lane & 31) == 0) {
            const size_t orow = (size_t)((row0 + lane) >> 5) * 128;
            out[orow + oc0 + j] = v;
            out[orow + 64 + oc0 + j] = w;
        }
    }
}

// ---------------------------------------------------------------------------
// SA2 fused, in-place single 32 KB buffer (gather -> h1 -> h2), each layer
// sweeps both oc-halves at once (32 accs, half the LDS reads). 32 KB LDS
// doubles co-residency vs R8 (2 -> 4 blocks/CU).
// ---------------------------------------------------------------------------
__global__ __launch_bounds__(256)
void sa2_fused(const float* __restrict__ l1xyz, const float* __restrict__ l1pts,
               const float* __restrict__ nxyz, const int* __restrict__ idx,
               const float* __restrict__ Wt0, const float* __restrict__ B0,
               const float* __restrict__ Wt1, const float* __restrict__ B1,
               const float* __restrict__ Wt2, const float* __restrict__ B2,
               float* __restrict__ out)
{
    __shared__ float buf[128][64];   // 32 KB: gather (swizzled) -> h1 -> h2
    const int tid = threadIdx.x, lane = tid & 63;
    const int wave = __builtin_amdgcn_readfirstlane(tid >> 6);
    const int gblk = blockIdx.x;
    const int b = gblk >> 7;
    const int row0 = gblk * 64;
    const int myi = idx[row0 + lane];
    const float* pc = l1xyz + ((size_t)b*512 + myi) * 3;
    const float f0 = pc[0] - nxyz[(size_t)gblk*3 + 0];
    const float f1 = pc[1] - nxyz[(size_t)gblk*3 + 1];
    const float f2 = pc[2] - nxyz[(size_t)gblk*3 + 2];
    for (int r = wave; r < 64; r += 4) {
        const int i2 = idx[row0 + r];
        const float* src = l1pts + ((size_t)b*512 + i2) * 128;
        buf[lane][r ^ lane]    = src[lane];
        buf[lane+64][r ^ lane] = src[lane + 64];
    }
    __syncthreads();
    const int oc0 = wave * 16;
    float aL[16], aH[16];
    // L1: 131 -> 128 (both halves; read swizzled gather, overwrite in place)
#pragma unroll
    for (int j = 0; j < 16; ++j) {
        aL[j] = B0[oc0+j]    + f0*Wt0[0*128+oc0+j]    + f1*Wt0[1*128+oc0+j]    + f2*Wt0[2*128+oc0+j];
        aH[j] = B0[64+oc0+j] + f0*Wt0[0*128+64+oc0+j] + f1*Wt0[1*128+64+oc0+j] + f2*Wt0[2*128+64+oc0+j];
    }
#pragma unroll 2
    for (int ci = 0; ci < 128; ++ci) {
        const float f = buf[ci][lane ^ (ci & 63)];
        const float* wp = Wt0 + (size_t)(ci+3)*128;
        fma16(aL, f, wp + oc0);
        fma16(aH, f, wp + 64 + oc0);
    }
    __syncthreads();
#pragma unroll
    for (int j = 0; j < 16; ++j) {
        buf[oc0+j][lane]    = fmaxf(aL[j], 0.f);
        buf[64+oc0+j][lane] = fmaxf(aH[j], 0.f);
    }
    __syncthreads();
    // L2: 128 -> 128 (both halves; in place)
#pragma unroll
    for (int j = 0; j < 16; ++j) { aL[j] = B1[oc0+j]; aH[j] = B1[64+oc0+j]; }
#pragma unroll 2
    for (int ci = 0; ci < 128; ++ci) {
        const float f = buf[ci][lane];
        const float* wp = Wt1 + (size_t)ci*128;
        fma16(aL, f, wp + oc0);
        fma16(aH, f, wp + 64 + oc0);
    }
    __syncthreads();
#pragma unroll
    for (int j = 0; j < 16; ++j) {
        buf[oc0+j][lane]    = fmaxf(aL[j], 0.f);
        buf[64+oc0+j][lane] = fmaxf(aH[j], 0.f);
    }
    __syncthreads();
    // L3: 128 -> 256 (two double-sweeps) + maxpool over K=64
    float* orow = out + (size_t)gblk * 256;
    for (int half = 0; half < 2; ++half) {
        const int oc = half*128 + oc0;
#pragma unroll
        for (int j = 0; j < 16; ++j) { aL[j] = B2[oc+j]; aH[j] = B2[64+oc+j]; }
#pragma unroll 2
        for (int ci = 0; ci < 128; ++ci) {
            const float f = buf[ci][lane];
            const float* wp = Wt2 + (size_t)ci*256;
            fma16(aL, f, wp + oc);
            fma16(aH, f, wp + 64 + oc);
        }
#pragma unroll
        for (int j = 0; j < 16; ++j) {
            float v = fmaxf(aL[j], 0.f);
            v = fmaxf(v, __shfl_xor(v, 1));
            v = fmaxf(v, __shfl_xor(v, 2));
            v = fmaxf(v, __shfl_xor(v, 4));
            v = fmaxf(v, __shfl_xor(v, 8));
            v = fmaxf(v, __shfl_xor(v, 16));
            v = fmaxf(v, __shfl_xor(v, 32));
            float w = fmaxf(aH[j], 0.f);
            w = fmaxf(w, __shfl_xor(w, 1));
            w = fmaxf(w, __shfl_xor(w, 2));
            w = fmaxf(w, __shfl_xor(w, 4));
            w = fmaxf(w, __shfl_xor(w, 8));
            w = fmaxf(w, __shfl_xor(w, 16));
            w = fmaxf(w, __shfl_xor(w, 32));
            if (lane == 0) { orow[oc + j] = v; orow[64 + oc + j] = w; }
        }
    }
}

// ---------------------------------------------------------------------------
// SA3 GEMM layers (unchanged)
// ---------------------------------------------------------------------------
template<int CIN, int COUT, bool CONCAT3, bool POOL>
__global__ __launch_bounds__(256)
void mlp_gemm_kernel(const float* __restrict__ inA, const float* __restrict__ inB,
                     const float* __restrict__ Wt, const float* __restrict__ Bb,
                     float* __restrict__ out)
{
    __shared__ float featS[128][64];
    const int tid = threadIdx.x, lane = tid & 63;
    const int wave = __builtin_amdgcn_readfirstlane(tid >> 6);
    const int row0 = blockIdx.x * 64;
    const int oc0 = blockIdx.y * 64 + wave * 16;
    float acc[16];
#pragma unroll
    for (int j = 0; j < 16; ++j) acc[j] = Bb[oc0 + j];
    for (int c0 = 0; c0 < CIN; c0 += 128) {
        const int csz = (CIN - c0 < 128) ? (CIN - c0) : 128;
        __syncthreads();
        for (int r = wave; r < 64; r += 4) {
            const int row = row0 + r;
            for (int cl = lane; cl < csz; cl += 64) {
                const int cig = c0 + cl;
                float v;
                if (CONCAT3)
                    v = (cig < 3) ? inA[(size_t)row*3 + cig]
                                  : inB[(size_t)row*(CIN-3) + (cig - 3)];
                else
                    v = inA[(size_t)row*CIN + cig];
                featS[cl][r ^ (cl & 63)] = v;
            }
        }
        __syncthreads();
        if (csz == 128) {
#pragma unroll 4
            for (int ci = 0; ci < 128; ++ci)
                fma16(acc, featS[ci][lane ^ (ci & 63)], Wt + (size_t)(c0+ci)*COUT + oc0);
        } else {
            for (int ci = 0; ci < csz; ++ci)
                fma16(acc, featS[ci][lane ^ (ci & 63)], Wt + (size_t)(c0+ci)*COUT + oc0);
        }
    }
    if (POOL) {
#pragma unroll
        for (int j = 0; j < 16; ++j) {
            float v = fmaxf(acc[j], 0.f);
            v = fmaxf(v, __shfl_xor(v, 1));
            v = fmaxf(v, __shfl_xor(v, 2));
            v = fmaxf(v, __shfl_xor(v, 4));
            v = fmaxf(v, __shfl_xor(v, 8));
            v = fmaxf(v, __shfl_xor(v, 16));
            v = fmaxf(v, __shfl_xor(v, 32));
            if (lane == 0) out[(size_t)blockIdx.x * COUT + oc0 + j] = v;
        }
    } else {
        float4 o0, o1, o2, o3;
        o0.x=fmaxf(acc[0],0.f);  o0.y=fmaxf(acc[1],0.f);  o0.z=fmaxf(acc[2],0.f);  o0.w=fmaxf(acc[3],0.f);
        o1.x=fmaxf(acc[4],0.f);  o1.y=fmaxf(acc[5],0.f);  o1.z=fmaxf(acc[6],0.f);  o1.w=fmaxf(acc[7],0.f);
        o2.x=fmaxf(acc[8],0.f);  o2.y=fmaxf(acc[9],0.f);  o2.z=fmaxf(acc[10],0.f); o2.w=fmaxf(acc[11],0.f);
        o3.x=fmaxf(acc[12],0.f); o3.y=fmaxf(acc[13],0.f); o3.z=fmaxf(acc[14],0.f); o3.w=fmaxf(acc[15],0.f);
        float4* op = (float4*)(out + (size_t)(row0 + lane)*COUT + oc0);
        op[0]=o0; op[1]=o1; op[2]=o2; op[3]=o3;
    }
}

// y[b][o] = fb[o] + max(pmax[2b], pmax[2b+1]) . fw[o]; one wave per output
__global__ __launch_bounds__(256)
void fc_kernel(const float* __restrict__ pmax, const float* __restrict__ fw,
               const float* __restrict__ fb, float* __restrict__ y)
{
    const int gw = (blockIdx.x * 256 + threadIdx.x) >> 6;
    const int lane = threadIdx.x & 63;
    const int b = gw >> 10, o = gw & 1023;
    const float4* g0 = (const float4*)(pmax + (size_t)(2*b) * 1024);
    const float4* g1 = (const float4*)(pmax + (size_t)(2*b+1) * 1024);
    const float4* wv = (const float4*)(fw + (size_t)o * 1024);
    float acc = 0.f;
#pragma unroll
    for (int r = 0; r < 4; ++r) {
        const float4 a = g0[lane + r*64];
        const float4 c = g1[lane + r*64];
        const float4 w = wv[lane + r*64];
        acc += fmaxf(a.x,c.x)*w.x + fmaxf(a.y,c.y)*w.y
             + fmaxf(a.z,c.z)*w.z + fmaxf(a.w,c.w)*w.w;
    }
#pragma unroll
    for (int m = 32; m >= 1; m >>= 1) acc += __shfl_xor(acc, m);
    if (lane == 0) y[gw] = acc + fb[o];
}

extern "C" void kernel_launch(void* const* d_in, const int* in_sizes, int n_in,
                              void* d_out, int out_size, void* d_ws, size_t ws_size,
                              hipStream_t stream)
{
    (void)in_sizes; (void)n_in; (void)out_size; (void)ws_size;
    const float* x   = (const float*)d_in[0];
    const float* s1w0 = (const float*)d_in[1];  const float* s1b0 = (const float*)d_in[2];
    const float* s1w1 = (const float*)d_in[3];  const float* s1b1 = (const float*)d_in[4];
    const float* s1w2 = (const float*)d_in[5];  const float* s1b2 = (const float*)d_in[6];
    const float* s2w0 = (const float*)d_in[7];  const float* s2b0 = (const float*)d_in[8];
    const float* s2w1 = (const float*)d_in[9];  const float* s2b1 = (const float*)d_in[10];
    const float* s2w2 = (const float*)d_in[11]; const float* s2b2 = (const float*)d_in[12];
    const float* s3w0 = (const float*)d_in[13]; const float* s3b0 = (const float*)d_in[14];
    const float* s3w1 = (const float*)d_in[15]; const float* s3b1 = (const float*)d_in[16];
    const float* s3w2 = (const float*)d_in[17]; const float* s3b2 = (const float*)d_in[18];
    const float* fw  = (const float*)d_in[19]; const float* fb  = (const float*)d_in[20];
    float* y = (float*)d_out;

    char* ws = (char*)d_ws;
    float* l1_xyz = (float*)(ws + 0);          // 16*512*3
    int*   idx1   = (int*)  (ws + 98304);      // 16*512*32
    float* l1_pts = (float*)(ws + 1146880);    // 16*512*128
    float* l2_xyz = (float*)(ws + 5341184);    // 16*128*3
    int*   idx2   = (int*)  (ws + 5365760);    // 16*128*64
    float* l2_pts = (float*)(ws + 5890048);    // 16*128*256
    float* h1     = (float*)(ws + 7987200);    // 2048*256
    float* h2     = (float*)(ws + 10084352);   // 2048*512
    float* pmax   = (float*)(ws + 14278656);   // 32*1024 partial maxes
    float* wt1_0  = (float*)(ws + 14409728);   // [3][64]
    float* wt1_1  = (float*)(ws + 14410496);   // [64][64]
    float* wt1_2  = (float*)(ws + 14426880);   // [64][128]
    float* wt2_0  = (float*)(ws + 14459648);   // [131][128]
    float* wt2_1  = (float*)(ws + 14526720);   // [128][128]
    float* wt2_2  = (float*)(ws + 14592256);   // [128][256]
    float* wt3_0  = (float*)(ws + 14723328);   // [259][256]
    float* wt3_1  = (float*)(ws + 14988544);   // [256][512]
    float* wt3_2  = (float*)(ws + 15512832);   // [512][1024]

    const float r2_1 = (float)(0.2 * 0.2);
    const float r2_2 = (float)(0.4 * 0.4);

    transpose_all<<<3126, 256, 0, stream>>>(
        s1w0, wt1_0, s1w1, wt1_1, s1w2, wt1_2,
        s2w0, wt2_0, s2w1, wt2_1, s2w2, wt2_2,
        s3w0, wt3_0, s3w1, wt3_1, s3w2, wt3_2);

    fps_fused<4096, 512, 128, 256><<<BATCH, 256, 0, stream>>>(x, l1_xyz, l2_xyz);
    ballq_kernel<4096, 512, 32><<<(BATCH*512)/4, 256, 0, stream>>>(x, l1_xyz, idx1, r2_1);
    sa1_fused<<<(BATCH*512*32)/64, 256, 0, stream>>>(x, l1_xyz, idx1,
        wt1_0, s1b0, wt1_1, s1b1, wt1_2, s1b2, l1_pts);
    ballq_kernel<512, 128, 64><<<(BATCH*128)/4, 256, 0, stream>>>(l1_xyz, l2_xyz, idx2, r2_2);
    sa2_fused<<<BATCH*128, 256, 0, stream>>>(l1_xyz, l1_pts, l2_xyz, idx2,
        wt2_0, s2b0, wt2_1, s2b1, wt2_2, s2b2, l2_pts);
    mlp_gemm_kernel<259, 256,  true,  false><<<dim3(32, 4),  256, 0, stream>>>(l2_xyz, l2_pts, wt3_0, s3b0, h1);
    mlp_gemm_kernel<256, 512,  false, false><<<dim3(32, 8),  256, 0, stream>>>(h1, nullptr, wt3_1, s3b1, h2);
    mlp_gemm_kernel<512, 1024, false, true ><<<dim3(32, 16), 256, 0, stream>>>(h2, nullptr, wt3_2, s3b2, pmax);
    fc_kernel<<<(BATCH*1024)/4, 256, 0, stream>>>(pmax, fw, fb, y);
}

// Round 10
// 939.514 us; speedup vs baseline: 1.2465x; 1.0090x over previous
//
#include <hip/hip_runtime.h>

#ifndef BATCH
#define BATCH 16
#endif

typedef float f32x2 __attribute__((ext_vector_type(2)));
__device__ __forceinline__ f32x2 mk2(float a, float b) { f32x2 r; r.x = a; r.y = b; return r; }

// ---- DPP wave64 reduction helpers (row_shr scan + row_bcast merge) --------
template<int CTRL>
__device__ __forceinline__ float dppmaxf(float v)
{
    const int d = __builtin_amdgcn_update_dpp(__float_as_int(v), __float_as_int(v),
                                              CTRL, 0xf, 0xf, false);
    return fmaxf(v, __int_as_float(d));
}
template<int CTRL>
__device__ __forceinline__ unsigned dppminu(unsigned v)
{
    const unsigned d = (unsigned)__builtin_amdgcn_update_dpp((int)v, (int)v,
                                                             CTRL, 0xf, 0xf, false);
    return (d < v) ? d : v;
}
__device__ __forceinline__ float wave_max_bcast(float v)
{
    v = dppmaxf<0x111>(v);
    v = dppmaxf<0x112>(v);
    v = dppmaxf<0x114>(v);
    v = dppmaxf<0x118>(v);
    v = dppmaxf<0x142>(v);
    v = dppmaxf<0x143>(v);
    return __int_as_float(__builtin_amdgcn_readlane(__float_as_int(v), 63));
}
__device__ __forceinline__ unsigned wave_min_bcast(unsigned v)
{
    v = dppminu<0x111>(v);
    v = dppminu<0x112>(v);
    v = dppminu<0x114>(v);
    v = dppminu<0x118>(v);
    v = dppminu<0x142>(v);
    v = dppminu<0x143>(v);
    return (unsigned)__builtin_amdgcn_readlane((int)v, 63);
}

// ---------------------------------------------------------------------------
// Fused FPS (both stages). One block per batch, BLOCK=256 (1 wave/SIMD).
// Per step: dist update; DPP value-max + index-min wave reduce; each wave
// ds_writes its pk to its OWN slot (parity double-buffered wslot[2][4] -- no
// atomic, no zeroing); barrier; every thread reads 4 pks + 3-compare tree.
// Parity race-free: write@s+2 to buffer (s&1) is separated from read@s by
// barrier s+1. No global stores inside loops (R8 lesson).
// Bit-exact: contract(off), (dx*dx+dy*dy)+dz*dz, strict-> first-index argmax
// (pk = dist_bits<<32 | ~idx; indices disjoint across waves -> no ties).
// ---------------------------------------------------------------------------
template<int N, int NP1, int NP2, int BLOCK>
__global__ __launch_bounds__(BLOCK)
void fps_fused(const float* __restrict__ xyz,
               float* __restrict__ out1, float* __restrict__ out2)
{
#pragma clang fp contract(off)
    constexpr int P  = N / BLOCK;
    constexpr int P2 = NP1 / BLOCK;
    constexpr int NW = BLOCK / 64;
    __shared__ float sx[N], sy[N], sz[N];
    __shared__ float s2x[NP1], s2y[NP1], s2z[NP1];
    __shared__ float o2x[NP2], o2y[NP2], o2z[NP2];
    __shared__ unsigned long long wslot[2][NW];
    const int b = blockIdx.x, t = threadIdx.x;
    const int lane = t & 63, wv = t >> 6;
    const float* xb = xyz + (size_t)b * N * 3;
    float px[P], py[P], pz[P], dist[P];
#pragma unroll
    for (int j = 0; j < P; ++j) {
        const int i = t + j * BLOCK;
        const float x = xb[i*3+0], y = xb[i*3+1], z = xb[i*3+2];
        sx[i] = x; sy[i] = y; sz[i] = z;
        px[j] = x; py[j] = y; pz[j] = z;
        dist[j] = 1e10f;
    }
    __syncthreads();
    float fx = sx[0], fy = sy[0], fz = sz[0];
    if (t == 0) { s2x[0] = fx; s2y[0] = fy; s2z[0] = fz; }
    for (int s = 1; s < NP1; ++s) {
        float bestv = -1.f; int besti = 0;
#pragma unroll
        for (int j = 0; j < P; ++j) {
            const float dx = px[j]-fx, dy = py[j]-fy, dz = pz[j]-fz;
            const float d = (dx*dx + dy*dy) + dz*dz;
            const float nd = fminf(dist[j], d);
            dist[j] = nd;
            if (nd > bestv) { bestv = nd; besti = t + j * BLOCK; }
        }
        const float wm = wave_max_bcast(bestv);
        const unsigned cand = (bestv == wm) ? (unsigned)besti : 0xffffffffu;
        const unsigned wi = wave_min_bcast(cand);
        const int par = s & 1;
        if (lane == 0)
            wslot[par][wv] = ((unsigned long long)__float_as_uint(wm) << 32)
                           | (unsigned)(~wi);
        __syncthreads();
        unsigned long long pa = wslot[par][0];
#pragma unroll
        for (int w = 1; w < NW; ++w) {
            const unsigned long long pb = wslot[par][w];
            pa = (pb > pa) ? pb : pa;
        }
        const int far = (int)(~(unsigned)pa);
        fx = sx[far]; fy = sy[far]; fz = sz[far];
        if (t == 0) { s2x[s] = fx; s2y[s] = fy; s2z[s] = fz; }
    }
    __syncthreads();
    // -------- stage 2 --------
    float mx[P2], my[P2], mz[P2], d2[P2];
#pragma unroll
    for (int j = 0; j < P2; ++j) {
        const int i = t + j * BLOCK;
        mx[j] = s2x[i]; my[j] = s2y[i]; mz[j] = s2z[i];
        d2[j] = 1e10f;
    }
    fx = s2x[0]; fy = s2y[0]; fz = s2z[0];
    if (t == 0) { o2x[0] = fx; o2y[0] = fy; o2z[0] = fz; }
    for (int s = 1; s < NP2; ++s) {
        float bestv = -1.f; int besti = 0;
#pragma unroll
        for (int j = 0; j < P2; ++j) {
            const float dx = mx[j]-fx, dy = my[j]-fy, dz = mz[j]-fz;
            const float d = (dx*dx + dy*dy) + dz*dz;
            const float nd = fminf(d2[j], d);
            d2[j] = nd;
            if (nd > bestv) { bestv = nd; besti = t + j * BLOCK; }
        }
        const float wm = wave_max_bcast(bestv);
        const unsigned cand = (bestv == wm) ? (unsigned)besti : 0xffffffffu;
        const unsigned wi = wave_min_bcast(cand);
        const int par = s & 1;
        if (lane == 0)
            wslot[par][wv] = ((unsigned long long)__float_as_uint(wm) << 32)
                           | (unsigned)(~wi);
        __syncthreads();
        unsigned long long pa = wslot[par][0];
#pragma unroll
        for (int w = 1; w < NW; ++w) {
            const unsigned long long pb = wslot[par][w];
            pa = (pb > pa) ? pb : pa;
        }
        const int far2 = (int)(~(unsigned)pa);
        fx = s2x[far2]; fy = s2y[far2]; fz = s2z[far2];
        if (t == 0) { o2x[s] = fx; o2y[s] = fy; o2z[s] = fz; }
    }
    __syncthreads();
    for (int i = t; i < NP1; i += BLOCK) {
        out1[((size_t)b*NP1 + i)*3 + 0] = s2x[i];
        out1[((size_t)b*NP1 + i)*3 + 1] = s2y[i];
        out1[((size_t)b*NP1 + i)*3 + 2] = s2z[i];
    }
    for (int i = t; i < NP2; i += BLOCK) {
        out2[((size_t)b*NP2 + i)*3 + 0] = o2x[i];
        out2[((size_t)b*NP2 + i)*3 + 1] = o2y[i];
        out2[((size_t)b*NP2 + i)*3 + 2] = o2z[i];
    }
}

// ---------------------------------------------------------------------------
// Ball query body + combined kernel (both levels in one launch)
// ---------------------------------------------------------------------------
template<int N, int S, int K>
__device__ __forceinline__ void ballq_body(const float* __restrict__ xyz,
                                           const float* __restrict__ nxyz,
                                           int* __restrict__ idx, const float r2,
                                           const int bid, const int tid)
{
#pragma clang fp contract(off)
    const int gw = (bid * 256 + tid) >> 6;
    const int lane = tid & 63;
    const int b = gw / S, s = gw % S;
    const float* xb = xyz + (size_t)b * N * 3;
    const float qx = nxyz[((size_t)b*S + s)*3 + 0];
    const float qy = nxyz[((size_t)b*S + s)*3 + 1];
    const float qz = nxyz[((size_t)b*S + s)*3 + 2];
    int* op = idx + ((size_t)b*S + s) * K;
    int base = 0, first = -1;
    for (int c = 0; c < N; c += 64) {
        const int i = c + lane;
        const float dx = xb[i*3+0]-qx, dy = xb[i*3+1]-qy, dz = xb[i*3+2]-qz;
        const float d = (dx*dx + dy*dy) + dz*dz;
        const bool hit = !(d > r2);
        const unsigned long long m = __ballot(hit);
        if (first < 0 && m) first = c + __builtin_ctzll(m);
        const int pos = base + __popcll(m & ((1ull << lane) - 1ull));
        if (hit && pos < K) op[pos] = i;
        base += __popcll(m);
        if (base >= K) break;
    }
    if (base < K && lane >= base && lane < K) op[lane] = first;
}

__global__ __launch_bounds__(256)
void ballq_both(const float* __restrict__ pts1, const float* __restrict__ q1,
                int* __restrict__ idx1, const float r2a,
                const float* __restrict__ pts2, const float* __restrict__ q2,
                int* __restrict__ idx2, const float r2b)
{
    const int nb1 = (BATCH * 512) / 4;
    if ((int)blockIdx.x < nb1)
        ballq_body<4096, 512, 32>(pts1, q1, idx1, r2a, blockIdx.x, threadIdx.x);
    else
        ballq_body<512, 128, 64>(pts2, q2, idx2, r2b, blockIdx.x - nb1, threadIdx.x);
}

// ---------------------------------------------------------------------------
// All 9 weight transposes W[O][C] -> Wt[C][O] in one launch.
// ---------------------------------------------------------------------------
__global__ __launch_bounds__(256)
void transpose_all(const float* __restrict__ s0, float* __restrict__ d0,
                   const float* __restrict__ s1, float* __restrict__ d1,
                   const float* __restrict__ s2, float* __restrict__ d2,
                   const float* __restrict__ s3, float* __restrict__ d3,
                   const float* __restrict__ s4, float* __restrict__ d4,
                   const float* __restrict__ s5, float* __restrict__ d5,
                   const float* __restrict__ s6, float* __restrict__ d6,
                   const float* __restrict__ s7, float* __restrict__ d7,
                   const float* __restrict__ s8, float* __restrict__ d8)
{
    int i = blockIdx.x * 256 + threadIdx.x;
    if (i < 192)    { d0[(i%3)  *64   + i/3  ] = s0[i]; return; }  i -= 192;
    if (i < 4096)   { d1[(i&63) *64   + (i>>6)] = s1[i]; return; } i -= 4096;
    if (i < 8192)   { d2[(i&63) *128  + (i>>6)] = s2[i]; return; } i -= 8192;
    if (i < 16768)  { d3[(i%131)*128  + i/131] = s3[i]; return; }  i -= 16768;
    if (i < 16384)  { d4[(i&127)*128  + (i>>7)] = s4[i]; return; } i -= 16384;
    if (i < 32768)  { d5[(i&127)*256  + (i>>7)] = s5[i]; return; } i -= 32768;
    if (i < 66304)  { d6[(i%259)*256  + i/259] = s6[i]; return; }  i -= 66304;
    if (i < 131072) { d7[(i&255)*512  + (i>>8)] = s7[i]; return; } i -= 131072;
    if (i < 524288) { d8[(i&511)*1024 + (i>>9)] = s8[i]; return; }
}

// 8 packed FMAs (v_pk_fma_f32) against 16 contiguous transposed weights.
// Same IEEE fma per element as the scalar version -> bit-identical.
__device__ __forceinline__ void fma16pk(f32x2 (&acc)[8], const float f,
                                        const float* __restrict__ wrow)
{
    const float4 w0 = ((const float4*)wrow)[0];
    const float4 w1 = ((const float4*)wrow)[1];
    const float4 w2 = ((const float4*)wrow)[2];
    const float4 w3 = ((const float4*)wrow)[3];
    const f32x2 ff = mk2(f, f);
    acc[0] += ff * mk2(w0.x, w0.y);
    acc[1] += ff * mk2(w0.z, w0.w);
    acc[2] += ff * mk2(w1.x, w1.y);
    acc[3] += ff * mk2(w1.z, w1.w);
    acc[4] += ff * mk2(w2.x, w2.y);
    acc[5] += ff * mk2(w2.z, w2.w);
    acc[6] += ff * mk2(w3.x, w3.y);
    acc[7] += ff * mk2(w3.z, w3.w);
}

__device__ __forceinline__ float pool_half(float v)
{
    v = fmaxf(v, __shfl_xor(v, 1));
    v = fmaxf(v, __shfl_xor(v, 2));
    v = fmaxf(v, __shfl_xor(v, 4));
    v = fmaxf(v, __shfl_xor(v, 8));
    v = fmaxf(v, __shfl_xor(v, 16));
    return v;
}
__device__ __forceinline__ float pool_full(float v)
{
    v = pool_half(v);
    return fmaxf(v, __shfl_xor(v, 32));
}

// ---------------------------------------------------------------------------
// SA1 fused, in-place 16 KB buffer, packed-FMA accumulators.
// ---------------------------------------------------------------------------
__global__ __launch_bounds__(256)
void sa1_fused(const float* __restrict__ xyz, const float* __restrict__ nxyz,
               const int* __restrict__ idx,
               const float* __restrict__ Wt0, const float* __restrict__ B0,
               const float* __restrict__ Wt1, const float* __restrict__ B1,
               const float* __restrict__ Wt2, const float* __restrict__ B2,
               float* __restrict__ out)
{
    __shared__ float buf[64][64];
    const int tid = threadIdx.x, lane = tid & 63;
    const int wave = __builtin_amdgcn_readfirstlane(tid >> 6);
    const int row0 = blockIdx.x * 64;
    const int myrow = row0 + lane;
    const int g = myrow >> 5, b = g >> 9;
    const int i = idx[myrow];
    const float* p = xyz + ((size_t)b*4096 + i) * 3;
    const float f0 = p[0] - nxyz[(size_t)g*3 + 0];
    const float f1 = p[1] - nxyz[(size_t)g*3 + 1];
    const float f2 = p[2] - nxyz[(size_t)g*3 + 2];
    const int oc0 = wave * 16;
    f32x2 aL[8], aH[8];
    // L1: 3 -> 64
#pragma unroll
    for (int j = 0; j < 16; ++j) {
        const float v = B0[oc0+j] + f0*Wt0[0*64+oc0+j] + f1*Wt0[1*64+oc0+j] + f2*Wt0[2*64+oc0+j];
        buf[oc0+j][lane] = fmaxf(v, 0.f);
    }
    __syncthreads();
    // L2: 64 -> 64 (in place)
#pragma unroll
    for (int k = 0; k < 8; ++k) aL[k] = mk2(B1[oc0+2*k], B1[oc0+2*k+1]);
#pragma unroll 4
    for (int ci = 0; ci < 64; ++ci)
        fma16pk(aL, buf[ci][lane], Wt1 + ci*64 + oc0);
    __syncthreads();
#pragma unroll
    for (int k = 0; k < 8; ++k) {
        buf[oc0+2*k][lane]   = fmaxf(aL[k].x, 0.f);
        buf[oc0+2*k+1][lane] = fmaxf(aL[k].y, 0.f);
    }
    __syncthreads();
    // L3: 64 -> 128 both halves + maxpool over K=32
#pragma unroll
    for (int k = 0; k < 8; ++k) {
        aL[k] = mk2(B2[oc0+2*k], B2[oc0+2*k+1]);
        aH[k] = mk2(B2[64+oc0+2*k], B2[64+oc0+2*k+1]);
    }
#pragma unroll 2
    for (int ci = 0; ci < 64; ++ci) {
        const float f = buf[ci][lane];
        fma16pk(aL, f, Wt2 + ci*128 + oc0);
        fma16pk(aH, f, Wt2 + ci*128 + 64 + oc0);
    }
#pragma unroll
    for (int k = 0; k < 8; ++k) {
        const float v0 = pool_half(fmaxf(aL[k].x, 0.f));
        const float v1 = pool_half(fmaxf(aL[k].y, 0.f));
        const float w0 = pool_half(fmaxf(aH[k].x, 0.f));
        const float w1 = pool_half(fmaxf(aH[k].y, 0.f));
        if ((lane & 31) == 0) {
            const size_t orow = (size_t)((row0 + lane) >> 5) * 128;
            out[orow + oc0 + 2*k]       = v0;
            out[orow + oc0 + 2*k + 1]   = v1;
            out[orow + 64 + oc0 + 2*k]     = w0;
            out[orow + 64 + oc0 + 2*k + 1] = w1;
        }
    }
}

// ---------------------------------------------------------------------------
// SA2 fused, in-place 32 KB buffer, packed-FMA accumulators.
// ---------------------------------------------------------------------------
__global__ __launch_bounds__(256)
void sa2_fused(const float* __restrict__ l1xyz, const float* __restrict__ l1pts,
               const float* __restrict__ nxyz, const int* __restrict__ idx,
               const float* __restrict__ Wt0, const float* __restrict__ B0,
               const float* __restrict__ Wt1, const float* __restrict__ B1,
               const float* __restrict__ Wt2, const float* __restrict__ B2,
               float* __restrict__ out)
{
    __shared__ float buf[128][64];
    const int tid = threadIdx.x, lane = tid & 63;
    const int wave = __builtin_amdgcn_readfirstlane(tid >> 6);
    const int gblk = blockIdx.x;
    const int b = gblk >> 7;
    const int row0 = gblk * 64;
    const int myi = idx[row0 + lane];
    const float* pc = l1xyz + ((size_t)b*512 + myi) * 3;
    const float f0 = pc[0] - nxyz[(size_t)gblk*3 + 0];
    const float f1 = pc[1] - nxyz[(size_t)gblk*3 + 1];
    const float f2 = pc[2] - nxyz[(size_t)gblk*3 + 2];
    for (int r = wave; r < 64; r += 4) {
        const int i2 = idx[row0 + r];
        const float* src = l1pts + ((size_t)b*512 + i2) * 128;
        buf[lane][r ^ lane]    = src[lane];
        buf[lane+64][r ^ lane] = src[lane + 64];
    }
    __syncthreads();
    const int oc0 = wave * 16;
    f32x2 aL[8], aH[8];
    // L1: 131 -> 128 both halves (swizzled gather read, in-place overwrite)
#pragma unroll
    for (int k = 0; k < 8; ++k) {
        const int j0 = oc0 + 2*k, j1 = oc0 + 2*k + 1;
        aL[k] = mk2(B0[j0]    + f0*Wt0[j0]     + f1*Wt0[128+j0]    + f2*Wt0[256+j0],
                    B0[j1]    + f0*Wt0[j1]     + f1*Wt0[128+j1]    + f2*Wt0[256+j1]);
        aH[k] = mk2(B0[64+j0] + f0*Wt0[64+j0]  + f1*Wt0[192+j0]    + f2*Wt0[320+j0],
                    B0[64+j1] + f0*Wt0[64+j1]  + f1*Wt0[192+j1]    + f2*Wt0[320+j1]);
    }
#pragma unroll 2
    for (int ci = 0; ci < 128; ++ci) {
        const float f = buf[ci][lane ^ (ci & 63)];
        const float* wp = Wt0 + (size_t)(ci+3)*128;
        fma16pk(aL, f, wp + oc0);
        fma16pk(aH, f, wp + 64 + oc0);
    }
    __syncthreads();
#pragma unroll
    for (int k = 0; k < 8; ++k) {
        buf[oc0+2*k][lane]      = fmaxf(aL[k].x, 0.f);
        buf[oc0+2*k+1][lane]    = fmaxf(aL[k].y, 0.f);
        buf[64+oc0+2*k][lane]   = fmaxf(aH[k].x, 0.f);
        buf[64+oc0+2*k+1][lane] = fmaxf(aH[k].y, 0.f);
    }
    __syncthreads();
    // L2: 128 -> 128 both halves (in place)
#pragma unroll
    for (int k = 0; k < 8; ++k) {
        aL[k] = mk2(B1[oc0+2*k], B1[oc0+2*k+1]);
        aH[k] = mk2(B1[64+oc0+2*k], B1[64+oc0+2*k+1]);
    }
#pragma unroll 2
    for (int ci = 0; ci < 128; ++ci) {
        const float f = buf[ci][lane];
        const float* wp = Wt1 + (size_t)ci*128;
        fma16pk(aL, f, wp + oc0);
        fma16pk(aH, f, wp + 64 + oc0);
    }
    __syncthreads();
#pragma unroll
    for (int k = 0; k < 8; ++k) {
        buf[oc0+2*k][lane]      = fmaxf(aL[k].x, 0.f);
        buf[oc0+2*k+1][lane]    = fmaxf(aL[k].y, 0.f);
        buf[64+oc0+2*k][lane]   = fmaxf(aH[k].x, 0.f);
        buf[64+oc0+2*k+1][lane] = fmaxf(aH[k].y, 0.f);
    }
    __syncthreads();
    // L3: 128 -> 256 (two double-sweeps) + maxpool over K=64
    float* orow = out + (size_t)gblk * 256;
    for (int half = 0; half < 2; ++half) {
        const int oc = half*128 + oc0;
#pragma unroll
        for (int k = 0; k < 8; ++k) {
            aL[k] = mk2(B2[oc+2*k], B2[oc+2*k+1]);
            aH[k] = mk2(B2[64+oc+2*k], B2[64+oc+2*k+1]);
        }
#pragma unroll 2
        for (int ci = 0; ci < 128; ++ci) {
            const float f = buf[ci][lane];
            const float* wp = Wt2 + (size_t)ci*256;
            fma16pk(aL, f, wp + oc);
            fma16pk(aH, f, wp + 64 + oc);
        }
#pragma unroll
        for (int k = 0; k < 8; ++k) {
            const float v0 = pool_full(fmaxf(aL[k].x, 0.f));
            const float v1 = pool_full(fmaxf(aL[k].y, 0.f));
            const float w0 = pool_full(fmaxf(aH[k].x, 0.f));
            const float w1 = pool_full(fmaxf(aH[k].y, 0.f));
            if (lane == 0) {
                orow[oc + 2*k]        = v0;
                orow[oc + 2*k + 1]    = v1;
                orow[64 + oc + 2*k]   = w0;
                orow[64 + oc + 2*k+1] = w1;
            }
        }
    }
}

// ---------------------------------------------------------------------------
// SA3 GEMM layers, packed-FMA accumulators.
// ---------------------------------------------------------------------------
template<int CIN, int COUT, bool CONCAT3, bool POOL>
__global__ __launch_bounds__(256)
void mlp_gemm_kernel(const float* __restrict__ inA, const float* __restrict__ inB,
                     const float* __restrict__ Wt, const float* __restrict__ Bb,
                     float* __restrict__ out)
{
    __shared__ float featS[128][64];
    const int tid = threadIdx.x, lane = tid & 63;
    const int wave = __builtin_amdgcn_readfirstlane(tid >> 6);
    const int row0 = blockIdx.x * 64;
    const int oc0 = blockIdx.y * 64 + wave * 16;
    f32x2 acc[8];
#pragma unroll
    for (int k = 0; k < 8; ++k) acc[k] = mk2(Bb[oc0+2*k], Bb[oc0+2*k+1]);
    for (int c0 = 0; c0 < CIN; c0 += 128) {
        const int csz = (CIN - c0 < 128) ? (CIN - c0) : 128;
        __syncthreads();
        for (int r = wave; r < 64; r += 4) {
            const int row = row0 + r;
            for (int cl = lane; cl < csz; cl += 64) {
                const int cig = c0 + cl;
                float v;
                if (CONCAT3)
                    v = (cig < 3) ? inA[(size_t)row*3 + cig]
                                  : inB[(size_t)row*(CIN-3) + (cig - 3)];
                else
                    v = inA[(size_t)row*CIN + cig];
                featS[cl][r ^ (cl & 63)] = v;
            }
        }
        __syncthreads();
        if (csz == 128) {
#pragma unroll 4
            for (int ci = 0; ci < 128; ++ci)
                fma16pk(acc, featS[ci][lane ^ (ci & 63)], Wt + (size_t)(c0+ci)*COUT + oc0);
        } else {
            for (int ci = 0; ci < csz; ++ci)
                fma16pk(acc, featS[ci][lane ^ (ci & 63)], Wt + (size_t)(c0+ci)*COUT + oc0);
        }
    }
    if (POOL) {
#pragma unroll
        for (int k = 0; k < 8; ++k) {
            const float v0 = pool_full(fmaxf(acc[k].x, 0.f));
            const float v1 = pool_full(fmaxf(acc[k].y, 0.f));
            if (lane == 0) {
                out[(size_t)blockIdx.x * COUT + oc0 + 2*k]     = v0;
                out[(size_t)blockIdx.x * COUT + oc0 + 2*k + 1] = v1;
            }
        }
    } else {
        float4 o0, o1, o2, o3;
        o0.x=fmaxf(acc[0].x,0.f); o0.y=fmaxf(acc[0].y,0.f); o0.z=fmaxf(acc[1].x,0.f); o0.w=fmaxf(acc[1].y,0.f);
        o1.x=fmaxf(acc[2].x,0.f); o1.y=fmaxf(acc[2].y,0.f); o1.z=fmaxf(acc[3].x,0.f); o1.w=fmaxf(acc[3].y,0.f);
        o2.x=fmaxf(acc[4].x,0.f); o2.y=fmaxf(acc[4].y,0.f); o2.z=fmaxf(acc[5].x,0.f); o2.w=fmaxf(acc[5].y,0.f);
        o3.x=fmaxf(acc[6].x,0.f); o3.y=fmaxf(acc[6].y,0.f); o3.z=fmaxf(acc[7].x,0.f); o3.w=fmaxf(acc[7].y,0.f);
        float4* op = (float4*)(out + (size_t)(row0 + lane)*COUT + oc0);
        op[0]=o0; op[1]=o1; op[2]=o2; op[3]=o3;
    }
}

// y[b][o] = fb[o] + max(pmax[2b], pmax[2b+1]) . fw[o]; one wave per output
__global__ __launch_bounds__(256)
void fc_kernel(const float* __restrict__ pmax, const float* __restrict__ fw,
               const float* __restrict__ fb, float* __restrict__ y)
{
    const int gw = (blockIdx.x * 256 + threadIdx.x) >> 6;
    const int lane = threadIdx.x & 63;
    const int b = gw >> 10, o = gw & 1023;
    const float4* g0 = (const float4*)(pmax + (size_t)(2*b) * 1024);
    const float4* g1 = (const float4*)(pmax + (size_t)(2*b+1) * 1024);
    const float4* wv = (const float4*)(fw + (size_t)o * 1024);
    float acc = 0.f;
#pragma unroll
    for (int r = 0; r < 4; ++r) {
        const float4 a = g0[lane + r*64];
        const float4 c = g1[lane + r*64];
        const float4 w = wv[lane + r*64];
        acc += fmaxf(a.x,c.x)*w.x + fmaxf(a.y,c.y)*w.y
             + fmaxf(a.z,c.z)*w.z + fmaxf(a.w,c.w)*w.w;
    }
#pragma unroll
    for (int m = 32; m >= 1; m >>= 1) acc += __shfl_xor(acc, m);
    if (lane == 0) y[gw] = acc + fb[o];
}

extern "C" void kernel_launch(void* const* d_in, const int* in_sizes, int n_in,
                              void* d_out, int out_size, void* d_ws, size_t ws_size,
                              hipStream_t stream)
{
    (void)in_sizes; (void)n_in; (void)out_size; (void)ws_size;
    const float* x   = (const float*)d_in[0];
    const float* s1w0 = (const float*)d_in[1];  const float* s1b0 = (const float*)d_in[2];
    const float* s1w1 = (const float*)d_in[3];  const float* s1b1 = (const float*)d_in[4];
    const float* s1w2 = (const float*)d_in[5];  const float* s1b2 = (const float*)d_in[6];
    const float* s2w0 = (const float*)d_in[7];  const float* s2b0 = (const float*)d_in[8];
    const float* s2w1 = (const float*)d_in[9];  const float* s2b1 = (const float*)d_in[10];
    const float* s2w2 = (const float*)d_in[11]; const float* s2b2 = (const float*)d_in[12];
    const float* s3w0 = (const float*)d_in[13]; const float* s3b0 = (const float*)d_in[14];
    const float* s3w1 = (const float*)d_in[15]; const float* s3b1 = (const float*)d_in[16];
    const float* s3w2 = (const float*)d_in[17]; const float* s3b2 = (const float*)d_in[18];
    const float* fw  = (const float*)d_in[19]; const float* fb  = (const float*)d_in[20];
    float* y = (float*)d_out;

    char* ws = (char*)d_ws;
    float* l1_xyz = (float*)(ws + 0);          // 16*512*3
    int*   idx1   = (int*)  (ws + 98304);      // 16*512*32
    float* l1_pts = (float*)(ws + 1146880);    // 16*512*128
    float* l2_xyz = (float*)(ws + 5341184);    // 16*128*3
    int*   idx2   = (int*)  (ws + 5365760);    // 16*128*64
    float* l2_pts = (float*)(ws + 5890048);    // 16*128*256
    float* h1     = (float*)(ws + 7987200);    // 2048*256
    float* h2     = (float*)(ws + 10084352);   // 2048*512
    float* pmax   = (float*)(ws + 14278656);   // 32*1024 partial maxes
    float* wt1_0  = (float*)(ws + 14409728);   // [3][64]
    float* wt1_1  = (float*)(ws + 14410496);   // [64][64]
    float* wt1_2  = (float*)(ws + 14426880);   // [64][128]
    float* wt2_0  = (float*)(ws + 14459648);   // [131][128]
    float* wt2_1  = (float*)(ws + 14526720);   // [128][128]
    float* wt2_2  = (float*)(ws + 14592256);   // [128][256]
    float* wt3_0  = (float*)(ws + 14723328);   // [259][256]
    float* wt3_1  = (float*)(ws + 14988544);   // [256][512]
    float* wt3_2  = (float*)(ws + 15512832);   // [512][1024]

    const float r2_1 = (float)(0.2 * 0.2);
    const float r2_2 = (float)(0.4 * 0.4);

    transpose_all<<<3126, 256, 0, stream>>>(
        s1w0, wt1_0, s1w1, wt1_1, s1w2, wt1_2,
        s2w0, wt2_0, s2w1, wt2_1, s2w2, wt2_2,
        s3w0, wt3_0, s3w1, wt3_1, s3w2, wt3_2);

    fps_fused<4096, 512, 128, 256><<<BATCH, 256, 0, stream>>>(x, l1_xyz, l2_xyz);
    ballq_both<<<(BATCH*512)/4 + (BATCH*128)/4, 256, 0, stream>>>(
        x, l1_xyz, idx1, r2_1, l1_xyz, l2_xyz, idx2, r2_2);
    sa1_fused<<<(BATCH*512*32)/64, 256, 0, stream>>>(x, l1_xyz, idx1,
        wt1_0, s1b0, wt1_1, s1b1, wt1_2, s1b2, l1_pts);
    sa2_fused<<<BATCH*128, 256, 0, stream>>>(l1_xyz, l1_pts, l2_xyz, idx2,
        wt2_0, s2b0, wt2_1, s2b1, wt2_2, s2b2, l2_pts);
    mlp_gemm_kernel<259, 256,  true,  false><<<dim3(32, 4),  256, 0, stream>>>(l2_xyz, l2_pts, wt3_0, s3b0, h1);
    mlp_gemm_kernel<256, 512,  false, false><<<dim3(32, 8),  256, 0, stream>>>(h1, nullptr, wt3_1, s3b1, h2);
    mlp_gemm_kernel<512, 1024, false, true ><<<dim3(32, 16), 256, 0, stream>>>(h2, nullptr, wt3_2, s3b2, pmax);
    fc_kernel<<<(BATCH*1024)/4, 256, 0, stream>>>(pmax, fw, fb, y);
}